// Round 11
// baseline (285.969 us; speedup 1.0000x reference)
//
#include <hip/hip_runtime.h>
#include <stdint.h>

#define B_  2
#define S_  2048
#define D_  2048
#define H_  16
#define HD_ 128
#define D3_ 6144

typedef unsigned short u16;
typedef __attribute__((ext_vector_type(8))) __bf16 bf16x8;
typedef __attribute__((ext_vector_type(4))) float f32x4;
typedef __attribute__((ext_vector_type(8))) u16  u16x8;
typedef __attribute__((ext_vector_type(4))) u16  u16x4;
typedef __attribute__((ext_vector_type(2))) u16  u16x2;

__device__ inline u16 f2bf(float f) {
  union { float f; uint32_t u; } v; v.f = f;
  uint32_t r = v.u + 0x7FFFu + ((v.u >> 16) & 1u);
  return (u16)(r >> 16);
}
__device__ inline float bf2f(u16 u) {
  union { float f; uint32_t u; } v; v.u = ((uint32_t)u) << 16;
  return v.f;
}
__device__ inline void gload_lds16(const void* g, void* l) {
  __builtin_amdgcn_global_load_lds((const __attribute__((address_space(1))) uint32_t*)g,
                                   (__attribute__((address_space(3))) uint32_t*)l, 16, 0, 0);
}

// tile-boundary sync: own ds_reads consumed, own staged gloads landed, barrier.
#define TILE_SYNC() do { \
    asm volatile("s_waitcnt lgkmcnt(0)" ::: "memory"); \
    asm volatile("s_waitcnt vmcnt(0)" ::: "memory"); \
    __builtin_amdgcn_s_barrier(); \
    asm volatile("" ::: "memory"); \
  } while (0)

// ---------------- fp32 -> bf16 cast ----------------
__global__ __launch_bounds__(256) void castk(const float* __restrict__ in, u16* __restrict__ out, int n) {
  int i = blockIdx.x * 256 + threadIdx.x;
  int n8 = n >> 3;
  if (i < n8) {
    f32x4 a = ((const f32x4*)in)[2*i];
    f32x4 b = ((const f32x4*)in)[2*i + 1];
    u16x8 o;
#pragma unroll
    for (int j = 0; j < 4; ++j) o[j] = f2bf(a[j]);
#pragma unroll
    for (int j = 0; j < 4; ++j) o[4+j] = f2bf(b[j]);
    ((u16x8*)out)[i] = o;
  }
}

// ============ B^T GEMM, BM=BN=256, BK=64, 8 waves (2M x 4N, wave 128x64).
// R8 geometry + R8 interleaved MFMA order (best measured: 108.8us / 39.4%).
// One barrier per K-tile, straight-line interior. LDS 128KB double-buffered. ============
template<int BF16OUT>
__global__ __launch_bounds__(512, 2) void gemm8(const u16* __restrict__ A, const u16* __restrict__ Bw,
                                                void* __restrict__ Cp, int M, int N, int K) {
  __shared__ __align__(16) u16 lds_[65536];   // 128 KB: A[2][32KB] | B[2][32KB]
  char* ldsb = (char*)lds_;
  const int tid = threadIdx.x;
  const int w = tid >> 6, l = tid & 63;
  const int lr = l & 15, lg = l >> 4;
  const int wr = w >> 2, wc = w & 3;          // 2 x 4 waves
  const int nbn = (int)gridDim.x;
  const int nwg = nbn * (int)gridDim.y;
  const int bid = (int)(blockIdx.y * gridDim.x + blockIdx.x);
  const int swz = (bid & 7) * (nwg >> 3) + (bid >> 3);   // XCD swizzle (nwg%8==0)
  const int bm = swz / nbn, bn = swz % nbn;

  f32x4 acc[8][4] = {};

  int row4[4], col4[4];
#pragma unroll
  for (int i = 0; i < 4; ++i) {
    int off = i*8192 + tid*16;
    row4[i] = off >> 7;                              // 0..255
    col4[i] = (off & 127) ^ ((row4[i] & 7) << 4);    // involution source swizzle
  }
  const size_t rs = (size_t)K * 2;
  const char* Ab = (const char*)A + (size_t)bm * 256 * rs;
  const char* Bb = (const char*)Bw + (size_t)bn * 256 * rs;
  const int wb = w * 1024;

#define STG(T_) do { \
    char* dA_ = ldsb + ((T_)&1)*32768; \
    char* dB_ = ldsb + 65536 + ((T_)&1)*32768; \
    _Pragma("unroll") \
    for (int i_ = 0; i_ < 4; ++i_) \
      gload_lds16(Ab + (size_t)row4[i_]*rs + (size_t)(T_)*128 + col4[i_], dA_ + i_*8192 + wb); \
    _Pragma("unroll") \
    for (int i_ = 0; i_ < 4; ++i_) \
      gload_lds16(Bb + (size_t)row4[i_]*rs + (size_t)(T_)*128 + col4[i_], dB_ + i_*8192 + wb); \
  } while (0)

#define RD_A(dst, mf, ks) do { int row_ = wr*128 + (mf)*16 + lr; \
    dst = *(const bf16x8*)(La + row_*128 + (((ks)*64 + lg*16) ^ ((row_ & 7) << 4))); } while (0)
#define RD_B(dst, nf, ks) do { int row_ = wc*64 + (nf)*16 + lr; \
    dst = *(const bf16x8*)(Lb + row_*128 + (((ks)*64 + lg*16) ^ ((row_ & 7) << 4))); } while (0)

  const int NT = K >> 6;
  STG(0);
  TILE_SYNC();

  for (int T = 0; T < NT; ++T) {
    const char* La = ldsb + (T & 1)*32768;
    const char* Lb = ldsb + 65536 + (T & 1)*32768;
    if (T + 1 < NT) STG(T + 1);          // 8 gloads into the inactive buffer

    bf16x8 a0[4], a1[4], b0[4], b1[4];
    // half 0: mf 0-3
#pragma unroll
    for (int mf = 0; mf < 4; ++mf) { RD_A(a0[mf], mf, 0); RD_A(a1[mf], mf, 1); }
#pragma unroll
    for (int nf = 0; nf < 4; ++nf) { RD_B(b0[nf], nf, 0); RD_B(b1[nf], nf, 1); }
#pragma unroll
    for (int mf = 0; mf < 4; ++mf)
#pragma unroll
      for (int nf = 0; nf < 4; ++nf) {
        acc[mf][nf] = __builtin_amdgcn_mfma_f32_16x16x32_bf16(a0[mf], b0[nf], acc[mf][nf], 0, 0, 0);
        acc[mf][nf] = __builtin_amdgcn_mfma_f32_16x16x32_bf16(a1[mf], b1[nf], acc[mf][nf], 0, 0, 0);
      }
    // half 1: mf 4-7 (B frags reused from regs)
#pragma unroll
    for (int mf = 0; mf < 4; ++mf) { RD_A(a0[mf], mf + 4, 0); RD_A(a1[mf], mf + 4, 1); }
#pragma unroll
    for (int mf = 0; mf < 4; ++mf)
#pragma unroll
      for (int nf = 0; nf < 4; ++nf) {
        acc[mf+4][nf] = __builtin_amdgcn_mfma_f32_16x16x32_bf16(a0[mf], b0[nf], acc[mf+4][nf], 0, 0, 0);
        acc[mf+4][nf] = __builtin_amdgcn_mfma_f32_16x16x32_bf16(a1[mf], b1[nf], acc[mf+4][nf], 0, 0, 0);
      }
    TILE_SYNC();
  }
#undef STG
#undef RD_A
#undef RD_B

#pragma unroll
  for (int mf = 0; mf < 8; ++mf)
#pragma unroll
    for (int nf = 0; nf < 4; ++nf)
#pragma unroll
      for (int j = 0; j < 4; ++j) {
        int m = bm*256 + wr*128 + mf*16 + lg*4 + j;
        int n = bn*256 + wc*64 + nf*16 + lr;
        float v = acc[mf][nf][j];
        if (BF16OUT) ((u16*)Cp)[(size_t)m * N + n] = f2bf(v);
        else         ((float*)Cp)[(size_t)m * N + n] = v;
      }
}

// ---------------- 128x128 B^T GEMM, BK=64 dbuf, 1 barrier/K-tile, 2 blocks/CU ----------------
template<int BF16OUT>
__global__ __launch_bounds__(256, 2) void gemm_bt(const u16* __restrict__ A, const u16* __restrict__ Bw,
                                                  void* __restrict__ Cp, int M, int N, int K) {
  __shared__ __align__(16) u16 lds_[32768];   // 64 KB
  char* ldsb = (char*)lds_;
  const int tid = threadIdx.x;
  const int w = tid >> 6, l = tid & 63;
  const int lr = l & 15, lg = l >> 4;
  const int nwg = (int)(gridDim.x * gridDim.y);
  const int bid = (int)(blockIdx.y * gridDim.x + blockIdx.x);
  const int swz = (bid & 7) * (nwg >> 3) + (bid >> 3);
  const int bm = swz / (int)gridDim.x, bn = swz % (int)gridDim.x;
  const int wr = w >> 1, wc = w & 1;

  f32x4 acc[4][4] = {};

  int row4[4], col4[4];
#pragma unroll
  for (int i = 0; i < 4; ++i) {
    int off = i*4096 + tid*16;
    row4[i] = off >> 7;
    col4[i] = (off & 127) ^ ((row4[i] & 7) << 4);
  }
  const size_t rs = (size_t)K * 2;
  const char* Ab = (const char*)A + (size_t)bm * 128 * rs;
  const char* Bb = (const char*)Bw + (size_t)bn * 128 * rs;
  const int wb = w * 1024;

#define STG(T_) do { \
    char* dA_ = ldsb + ((T_)&1)*16384; \
    char* dB_ = ldsb + 32768 + ((T_)&1)*16384; \
    _Pragma("unroll") \
    for (int i_ = 0; i_ < 4; ++i_) \
      gload_lds16(Ab + (size_t)row4[i_]*rs + (size_t)(T_)*128 + col4[i_], dA_ + i_*4096 + wb); \
    _Pragma("unroll") \
    for (int i_ = 0; i_ < 4; ++i_) \
      gload_lds16(Bb + (size_t)row4[i_]*rs + (size_t)(T_)*128 + col4[i_], dB_ + i_*4096 + wb); \
  } while (0)

  const int NT = K >> 6;
  STG(0);
  TILE_SYNC();

  for (int T = 0; T < NT; ++T) {
    const char* La = ldsb + (T & 1)*16384;
    const char* Lb = ldsb + 32768 + (T & 1)*16384;
    if (T + 1 < NT) STG(T + 1);

    bf16x8 af[4][2], bf[4][2];
#pragma unroll
    for (int mt = 0; mt < 4; ++mt) {
      int row = wr*64 + mt*16 + lr;
#pragma unroll
      for (int ks = 0; ks < 2; ++ks)
        af[mt][ks] = *(const bf16x8*)(La + row*128 + ((ks*64 + lg*16) ^ ((row & 7) << 4)));
    }
#pragma unroll
    for (int nt = 0; nt < 4; ++nt) {
      int row = wc*64 + nt*16 + lr;
#pragma unroll
      for (int ks = 0; ks < 2; ++ks)
        bf[nt][ks] = *(const bf16x8*)(Lb + row*128 + ((ks*64 + lg*16) ^ ((row & 7) << 4)));
    }
#pragma unroll
    for (int mt = 0; mt < 4; ++mt)
#pragma unroll
      for (int nt = 0; nt < 4; ++nt) {
        acc[mt][nt] = __builtin_amdgcn_mfma_f32_16x16x32_bf16(af[mt][0], bf[nt][0], acc[mt][nt], 0, 0, 0);
        acc[mt][nt] = __builtin_amdgcn_mfma_f32_16x16x32_bf16(af[mt][1], bf[nt][1], acc[mt][nt], 0, 0, 0);
      }
    TILE_SYNC();
  }
#undef STG

#pragma unroll
  for (int mt = 0; mt < 4; ++mt)
#pragma unroll
    for (int nt = 0; nt < 4; ++nt)
#pragma unroll
      for (int j = 0; j < 4; ++j) {
        int m = bm*128 + wr*64 + mt*16 + lg*4 + j;
        int n = bn*128 + wc*64 + nt*16 + lr;
        float v = acc[mt][nt][j];
        if (BF16OUT) ((u16*)Cp)[(size_t)m * N + n] = f2bf(v);
        else         ((float*)Cp)[(size_t)m * N + n] = v;
      }
}

// ---------------- RoPE + per-head L2 norm (+attn_scale*log2e on Q) ----------------
__global__ __launch_bounds__(256) void rope_norm(const u16* __restrict__ qkv, const float* __restrict__ fc,
                                                 const float* __restrict__ scale_p,
                                                 u16* __restrict__ Qo, u16* __restrict__ Ko) {
  int gid = blockIdx.x;
  int bs = gid >> 2;
  int s = bs & (S_ - 1);
  int b = bs >> 11;
  int w = threadIdx.x >> 6, l = threadIdx.x & 63;
  int h = (gid & 3)*4 + w;
  float2 cs = ((const float2*)fc)[(size_t)s*64 + l];
  float scale = scale_p[0] * 1.4426950408889634f;  // fold log2(e) for exp2 softmax
  const u16* base = qkv + (size_t)bs * D3_;
  size_t obase = ((size_t)(b*H_ + h) * S_ + s) * HD_ + 2*l;
  {
    const u16* p = base + h*HD_ + 2*l;
    float x0 = bf2f(p[0]), x1 = bf2f(p[1]);
    float r0 = x0*cs.x - x1*cs.y;
    float r1 = x1*cs.x + x0*cs.y;
    float t = r0*r0 + r1*r1;
#pragma unroll
    for (int mk = 1; mk < 64; mk <<= 1) t += __shfl_xor(t, mk, 64);
    float inv = scale / (sqrtf(t) + 1e-6f);
    u16x2 o; o[0] = f2bf(r0*inv); o[1] = f2bf(r1*inv);
    *(u16x2*)(Qo + obase) = o;
  }
  {
    const u16* p = base + D_ + h*HD_ + 2*l;
    float x0 = bf2f(p[0]), x1 = bf2f(p[1]);
    float r0 = x0*cs.x - x1*cs.y;
    float r1 = x1*cs.x + x0*cs.y;
    float t = r0*r0 + r1*r1;
#pragma unroll
    for (int mk = 1; mk < 64; mk <<= 1) t += __shfl_xor(t, mk, 64);
    float inv = 1.0f / (sqrtf(t) + 1e-6f);
    u16x2 o; o[0] = f2bf(r0*inv); o[1] = f2bf(r1*inv);
    *(u16x2*)(Ko + obase) = o;
  }
}

// ---------------- V transpose: qkv v-slice [B,S,H,HD] -> Vt [B*H, HD, S] ----------------
__global__ __launch_bounds__(256) void v_trans(const u16* __restrict__ qkv, u16* __restrict__ Vt) {
  __shared__ u16 vt[64][136];
  int blk = blockIdx.x;
  int bh = blk >> 5, st = blk & 31;
  int b = bh >> 4, h = bh & 15;
  int s0 = st * 64;
  int tid = threadIdx.x;
#pragma unroll
  for (int i = 0; i < 4; ++i) {
    int idx = tid + i*256;
    int row = idx >> 4, ch = idx & 15;
    u16x8 v = *(const u16x8*)(qkv + (size_t)(b*S_ + s0 + row) * D3_ + 2*D_ + h*HD_ + ch*8);
    *(u16x8*)(&vt[row][ch*8]) = v;
  }
  __syncthreads();
#pragma unroll
  for (int p = 0; p < 2; ++p) {
    int d = p*64 + (tid >> 2);
    int q = (tid & 3) * 16;
    u16x8 t0, t1;
#pragma unroll
    for (int i = 0; i < 8; ++i) t0[i] = vt[q + i][d];
#pragma unroll
    for (int i = 0; i < 8; ++i) t1[i] = vt[q + 8 + i][d];
    u16* dst = Vt + ((size_t)bh * HD_ + d) * S_ + s0 + q;
    *(u16x8*)dst = t0;
    *(u16x8*)(dst + 8) = t1;
  }
}

// ---------------- causal flash attention: 4 waves x 32 q-rows (halved LDS traffic) ----------------
// QBLK=128, 4 waves (256 thr), KBLK=64. Swapped QK^T, lane-local softmax (2 q-halves).
// Each kf/vf LDS fragment feeds 2 MFMAs (q-halves in regs). K dbuf, V single-buf, vmcnt(4).
__global__ __launch_bounds__(256, 2) void flash_attn(const u16* __restrict__ Qh, const u16* __restrict__ Kh,
                                                     const u16* __restrict__ Vt, u16* __restrict__ AO) {
  __shared__ __align__(16) u16 lK[2][64*128];   // 32 KB
  __shared__ __align__(16) u16 lV[128*64];      // 16 KB
  __shared__ __align__(16) u16 lP[4][32*72];    // 18 KB
  const int i0 = (int)blockIdx.x;               // 0..511
  const int k5 = i0 & 255;
  const int bh = k5 >> 3;
  const int jj = k5 & 7;
  const int qt = (i0 < 256) ? (15 - jj) : jj;   // heavy half first
  const int tid = threadIdx.x, w = tid >> 6, l = tid & 63;   // w = 0..3
  const int lr = l & 15, lg = l >> 4;
  const int b = bh >> 4, h = bh & 15;

  bf16x8 qf[2][4];   // [q-half][ks]; q = qt*128 + w*32 + qh*16 + lr
#pragma unroll
  for (int qh = 0; qh < 2; ++qh) {
    const u16* qp = Qh + ((size_t)bh * S_ + qt*128 + w*32 + qh*16 + lr) * HD_ + lg*8;
#pragma unroll
    for (int ks = 0; ks < 4; ++ks) qf[qh][ks] = *(const bf16x8*)(qp + ks*32);
  }
  float m0[2], ls0[2];
  f32x4 oacc[2][8] = {};
#pragma unroll
  for (int qh = 0; qh < 2; ++qh) { m0[qh] = -__builtin_inff(); ls0[qh] = 0.f; }

  // staging: 256 thr x 16B x 4 passes = 16KB tile
  int krow[4], kcol[4], vrow[4], vcol[4], dstb[4];
#pragma unroll
  for (int p = 0; p < 4; ++p) {
    int off = p*4096 + tid*16;
    krow[p] = off >> 8; kcol[p] = (off & 255) ^ ((krow[p] & 7) << 4);
    vrow[p] = off >> 7; vcol[p] = (off & 127) ^ ((vrow[p] & 7) << 4);
    dstb[p] = p*4096 + w*1024;   // wave-uniform LDS dest base
  }
  const char* Kb = (const char*)(Kh + (size_t)bh * S_ * HD_);
  const char* Vb = (const char*)(Vt + (size_t)bh * HD_ * S_);

#define STAGE_K(nb, kt_) do {                                                       \
    _Pragma("unroll")                                                               \
    for (int p_ = 0; p_ < 4; ++p_)                                                  \
      gload_lds16(Kb + (size_t)((kt_)*64 + krow[p_])*256 + kcol[p_],                \
                  (char*)lK[nb] + dstb[p_]);                                        \
  } while (0)
#define STAGE_V(kt_) do {                                                           \
    _Pragma("unroll")                                                               \
    for (int p_ = 0; p_ < 4; ++p_)                                                  \
      gload_lds16(Vb + (size_t)vrow[p_]*(S_*2) + (kt_)*128 + vcol[p_],              \
                  (char*)lV + dstb[p_]);                                            \
  } while (0)

  const int nt = 2*qt + 2;
  STAGE_K(0, 0);
  STAGE_V(0);
  int cur = 0;
  for (int kt = 0; kt < nt; ++kt) {
    asm volatile("s_waitcnt vmcnt(4)" ::: "memory");   // K(cur)'s 4 loads done
    __builtin_amdgcn_s_barrier();
    asm volatile("" ::: "memory");
    const char* lKb = (const char*)lK[cur];

    // swapped QK^T: sc[qh][f][j] = S[k=kt*64+f*16+lg*4+j][q=qt*128+w*32+qh*16+lr]
    f32x4 sc[2][4] = {};
    __builtin_amdgcn_s_setprio(1);
#pragma unroll
    for (int ks = 0; ks < 4; ++ks) {
#pragma unroll
      for (int f = 0; f < 4; ++f) {
        int row = f*16 + lr;
        bf16x8 kf = *(const bf16x8*)(lKb + row*256 + ((ks*64 + lg*16) ^ ((row & 7) << 4)));
        sc[0][f] = __builtin_amdgcn_mfma_f32_16x16x32_bf16(kf, qf[0][ks], sc[0][f], 0, 0, 0);
        sc[1][f] = __builtin_amdgcn_mfma_f32_16x16x32_bf16(kf, qf[1][ks], sc[1][f], 0, 0, 0);
      }
    }
    __builtin_amdgcn_s_setprio(0);
    if (kt < nt-1) STAGE_K(cur ^ 1, kt + 1);   // prefetch next K under softmax

    if (kt >= nt-2) {  // diagonal tiles: mask k > q
#pragma unroll
      for (int qh = 0; qh < 2; ++qh)
#pragma unroll
        for (int f = 0; f < 4; ++f)
#pragma unroll
          for (int j = 0; j < 4; ++j)
            if (kt*64 + f*16 + lg*4 + j > qt*128 + w*32 + qh*16 + lr) sc[qh][f][j] = -__builtin_inff();
    }
    // lane-local online softmax per q-half
#pragma unroll
    for (int qh = 0; qh < 2; ++qh) {
      float pmax = sc[qh][0][0];
#pragma unroll
      for (int f = 0; f < 4; ++f)
#pragma unroll
        for (int j = 0; j < 4; ++j) pmax = fmaxf(pmax, sc[qh][f][j]);
      pmax = fmaxf(pmax, __shfl_xor(pmax, 16, 64));
      pmax = fmaxf(pmax, __shfl_xor(pmax, 32, 64));
      float mn = fmaxf(m0[qh], pmax);
      float resc = exp2f(m0[qh] - mn);
      m0[qh] = mn;
      float rsum = 0.f;
#pragma unroll
      for (int f = 0; f < 4; ++f)
#pragma unroll
        for (int j = 0; j < 4; ++j) {
          float p = exp2f(sc[qh][f][j] - mn);
          sc[qh][f][j] = p;
          rsum += p;
        }
      rsum += __shfl_xor(rsum, 16, 64);
      rsum += __shfl_xor(rsum, 32, 64);
      ls0[qh] = ls0[qh] * resc + rsum;
      // redistribute resc (uniform over lg) from lr-space to j-space
      float rescj[4];
#pragma unroll
      for (int j = 0; j < 4; ++j) rescj[j] = __shfl(resc, lg*4 + j, 64);
#pragma unroll
      for (int fd = 0; fd < 8; ++fd)
#pragma unroll
        for (int j = 0; j < 4; ++j) oacc[qh][fd][j] *= rescj[j];
      // P[q=qh*16+lr][k] packed write: one b64 per f
#pragma unroll
      for (int f = 0; f < 4; ++f) {
        u16x4 pk;
#pragma unroll
        for (int j = 0; j < 4; ++j) pk[j] = f2bf(sc[qh][f][j]);
        *(u16x4*)((char*)lP[w] + (qh*16 + lr)*144 + f*32 + lg*8) = pk;
      }
    }

    if (kt < nt-1) { asm volatile("s_waitcnt vmcnt(4)" ::: "memory"); }   // V(cur) done
    else           { asm volatile("s_waitcnt vmcnt(0)" ::: "memory"); }
    __builtin_amdgcn_s_barrier();
    asm volatile("" ::: "memory");
    // PV: vf shared across q-halves
    __builtin_amdgcn_s_setprio(1);
#pragma unroll
    for (int ks = 0; ks < 2; ++ks) {
      bf16x8 pf0 = *(const bf16x8*)((const char*)lP[w] + lr*144 + ks*64 + lg*16);
      bf16x8 pf1 = *(const bf16x8*)((const char*)lP[w] + (16 + lr)*144 + ks*64 + lg*16);
#pragma unroll
      for (int fd = 0; fd < 8; ++fd) {
        int row = fd*16 + lr;
        bf16x8 vf = *(const bf16x8*)((const char*)lV + row*128 + ((ks*64 + lg*16) ^ ((row & 7) << 4)));
        oacc[0][fd] = __builtin_amdgcn_mfma_f32_16x16x32_bf16(pf0, vf, oacc[0][fd], 0, 0, 0);
        oacc[1][fd] = __builtin_amdgcn_mfma_f32_16x16x32_bf16(pf1, vf, oacc[1][fd], 0, 0, 0);
      }
    }
    __builtin_amdgcn_s_setprio(0);
    asm volatile("" ::: "memory");
    __builtin_amdgcn_s_barrier();
    asm volatile("" ::: "memory");
    if (kt < nt-1) STAGE_V(kt + 1);
    cur ^= 1;
  }
#undef STAGE_K
#undef STAGE_V
  // epilogue: 1/ls redistributed to j-space, per q-half
#pragma unroll
  for (int qh = 0; qh < 2; ++qh) {
    float invl[4];
#pragma unroll
    for (int j = 0; j < 4; ++j) {
      float lsj = __shfl(ls0[qh], lg*4 + j, 64);
      invl[j] = 1.0f / lsj;
    }
#pragma unroll
    for (int fd = 0; fd < 8; ++fd)
#pragma unroll
      for (int j = 0; j < 4; ++j) {
        int qq = qt*128 + w*32 + qh*16 + lg*4 + j;
        int dd = fd*16 + lr;
        float v = oacc[qh][fd][j] * invl[j];
        AO[((size_t)b*S_ + qq)*D_ + h*HD_ + dd] = f2bf(v);
      }
  }
}

// ---------------- launch ----------------
extern "C" void kernel_launch(void* const* d_in, const int* in_sizes, int n_in,
                              void* d_out, int out_size, void* d_ws, size_t ws_size,
                              hipStream_t stream) {
  const float* x        = (const float*)d_in[0];
  const float* w_qkv    = (const float*)d_in[1];
  const float* w_out    = (const float*)d_in[2];
  const float* attn_sc  = (const float*)d_in[3];
  const float* freqs    = (const float*)d_in[4];

  if (ws_size < 167772160u) return;  // need 160 MB scratch

  char* ws = (char*)d_ws;
  u16* xbf  = (u16*)(ws);                 //  16 MB  [4096][2048]
  u16* wqbf = (u16*)(ws + 16777216);      //  24 MB  [6144][2048]
  u16* wobf = (u16*)(ws + 41943040);      //   8 MB  [2048][2048]
  u16* qkv  = (u16*)(ws + 50331648);      //  48 MB  [4096][6144]
  u16* Qh   = (u16*)(ws + 100663296);     //  16 MB  [B*H][S][HD]
  u16* Kh   = (u16*)(ws + 117440512);     //  16 MB  [B*H][S][HD]
  u16* Vt   = (u16*)(ws + 134217728);     //  16 MB  [B*H][HD][S]
  u16* AO   = (u16*)(ws + 150994944);     //  16 MB  [4096][2048]

  castk<<<4096, 256, 0, stream>>>(x,     xbf,  8388608);
  castk<<<6144, 256, 0, stream>>>(w_qkv, wqbf, 12582912);
  castk<<<2048, 256, 0, stream>>>(w_out, wobf, 4194304);

  // QKV: 256x256 tiles -> (24, 16) = 384 blocks
  gemm8<1><<<dim3(24, 16), 512, 0, stream>>>(xbf, wqbf, qkv, 4096, 6144, 2048);

  rope_norm<<<16384, 256, 0, stream>>>(qkv, freqs, attn_sc, Qh, Kh);
  v_trans<<<1024, 256, 0, stream>>>(qkv, Vt);

  flash_attn<<<512, 256, 0, stream>>>(Qh, Kh, Vt, AO);

  // out-projection: 128x128 tiles, (16, 32) = 512 blocks, 2 blocks/CU
  gemm_bt<0><<<dim3(16, 32), 256, 0, stream>>>(AO, wobf, (float*)d_out, 4096, 2048, 2048);
}

// Round 12
// 271.569 us; speedup vs baseline: 1.0530x; 1.0530x over previous
//
#include <hip/hip_runtime.h>
#include <stdint.h>

#define B_  2
#define S_  2048
#define D_  2048
#define H_  16
#define HD_ 128
#define D3_ 6144

typedef unsigned short u16;
typedef __attribute__((ext_vector_type(8))) __bf16 bf16x8;
typedef __attribute__((ext_vector_type(4))) float f32x4;
typedef __attribute__((ext_vector_type(8))) u16  u16x8;
typedef __attribute__((ext_vector_type(4))) u16  u16x4;
typedef __attribute__((ext_vector_type(2))) u16  u16x2;

__device__ inline u16 f2bf(float f) {
  union { float f; uint32_t u; } v; v.f = f;
  uint32_t r = v.u + 0x7FFFu + ((v.u >> 16) & 1u);
  return (u16)(r >> 16);
}
__device__ inline float bf2f(u16 u) {
  union { float f; uint32_t u; } v; v.u = ((uint32_t)u) << 16;
  return v.f;
}
__device__ inline void gload_lds16(const void* g, void* l) {
  __builtin_amdgcn_global_load_lds((const __attribute__((address_space(1))) uint32_t*)g,
                                   (__attribute__((address_space(3))) uint32_t*)l, 16, 0, 0);
}

// tile-boundary sync with full drain (used by gemm_bt only; gemm8 uses counted vmcnt)
#define TILE_SYNC() do { \
    asm volatile("s_waitcnt lgkmcnt(0)" ::: "memory"); \
    asm volatile("s_waitcnt vmcnt(0)" ::: "memory"); \
    __builtin_amdgcn_s_barrier(); \
    asm volatile("" ::: "memory"); \
  } while (0)

#define BARC() do { asm volatile("" ::: "memory"); __builtin_amdgcn_s_barrier(); asm volatile("" ::: "memory"); } while (0)

// ---------------- fp32 -> bf16 cast ----------------
__global__ __launch_bounds__(256) void castk(const float* __restrict__ in, u16* __restrict__ out, int n) {
  int i = blockIdx.x * 256 + threadIdx.x;
  int n8 = n >> 3;
  if (i < n8) {
    f32x4 a = ((const f32x4*)in)[2*i];
    f32x4 b = ((const f32x4*)in)[2*i + 1];
    u16x8 o;
#pragma unroll
    for (int j = 0; j < 4; ++j) o[j] = f2bf(a[j]);
#pragma unroll
    for (int j = 0; j < 4; ++j) o[4+j] = f2bf(b[j]);
    ((u16x8*)out)[i] = o;
  }
}

// ============ B^T GEMM, BM=BN=256, BK=64, 8 waves (2M x 4N, wave 128x64).
// COUNTED-VMCNT pipeline (T4): 2 phases/tile, 2 barriers/tile, loads stay in
// flight across barriers. ph1 {rd A-lo + B; stage A(T+1); 32 MFMA} | mid-bar |
// ph2 {rd A-hi; stage B(T+2) into freed half; 32 MFMA}. Top-of-tile vmcnt(4). ============
template<int BF16OUT>
__global__ __launch_bounds__(512, 2) void gemm8(const u16* __restrict__ A, const u16* __restrict__ Bw,
                                                void* __restrict__ Cp, int M, int N, int K) {
  __shared__ __align__(16) u16 lds_[65536];   // 128 KB: A[2][32KB] | B[2][32KB]
  char* ldsb = (char*)lds_;
  const int tid = threadIdx.x;
  const int w = tid >> 6, l = tid & 63;
  const int lr = l & 15, lg = l >> 4;
  const int wr = w >> 2, wc = w & 3;          // 2 x 4 waves
  const int nbn = (int)gridDim.x;
  const int nwg = nbn * (int)gridDim.y;
  const int bid = (int)(blockIdx.y * gridDim.x + blockIdx.x);
  const int swz = (bid & 7) * (nwg >> 3) + (bid >> 3);   // XCD swizzle (nwg%8==0)
  const int bm = swz / nbn, bn = swz % nbn;

  f32x4 acc[8][4] = {};

  int row4[4], col4[4];
#pragma unroll
  for (int i = 0; i < 4; ++i) {
    int off = i*8192 + tid*16;
    row4[i] = off >> 7;                              // 0..255
    col4[i] = (off & 127) ^ ((row4[i] & 7) << 4);    // involution source swizzle
  }
  const size_t rs = (size_t)K * 2;
  const char* Ab = (const char*)A + (size_t)bm * 256 * rs;
  const char* Bb = (const char*)Bw + (size_t)bn * 256 * rs;
  const int wb = w * 1024;

#define STG_A(T_) do { \
    char* dA_ = ldsb + ((T_)&1)*32768; \
    _Pragma("unroll") \
    for (int i_ = 0; i_ < 4; ++i_) \
      gload_lds16(Ab + (size_t)row4[i_]*rs + (size_t)(T_)*128 + col4[i_], dA_ + i_*8192 + wb); \
  } while (0)
#define STG_B(T_) do { \
    char* dB_ = ldsb + 65536 + ((T_)&1)*32768; \
    _Pragma("unroll") \
    for (int i_ = 0; i_ < 4; ++i_) \
      gload_lds16(Bb + (size_t)row4[i_]*rs + (size_t)(T_)*128 + col4[i_], dB_ + i_*8192 + wb); \
  } while (0)

#define RD_A(dst, mf, ks) do { int row_ = wr*128 + (mf)*16 + lr; \
    dst = *(const bf16x8*)(La + row_*128 + (((ks)*64 + lg*16) ^ ((row_ & 7) << 4))); } while (0)
#define RD_B(dst, nf, ks) do { int row_ = wc*64 + (nf)*16 + lr; \
    dst = *(const bf16x8*)(Lb + row_*128 + (((ks)*64 + lg*16) ^ ((row_ & 7) << 4))); } while (0)

  const int NT = K >> 6;
  // prologue: A(0), B(0) oldest; B(1) newest (stays in flight at first vmcnt(4))
  STG_A(0); STG_B(0); STG_B(1);

  for (int T = 0; T < NT; ++T) {
    // counted wait: A(T), B(T) are among the oldest; only the 4 newest (B/A in
    // flight for future tiles) may remain airborne. Never drains mid-loop.
    if (T < NT-1) { asm volatile("s_waitcnt vmcnt(4)" ::: "memory"); }
    else          { asm volatile("s_waitcnt vmcnt(0)" ::: "memory"); }
    __builtin_amdgcn_s_barrier();
    asm volatile("" ::: "memory");
    const char* La = ldsb + (T & 1)*32768;
    const char* Lb = ldsb + 65536 + (T & 1)*32768;

    bf16x8 a0[4], a1[4], b0[4], b1[4];
    // ---- ph1: read A mf0-3 + all B; stage A(T+1) (other A buffer); 32 MFMA
#pragma unroll
    for (int mf = 0; mf < 4; ++mf) { RD_A(a0[mf], mf, 0); RD_A(a1[mf], mf, 1); }
#pragma unroll
    for (int nf = 0; nf < 4; ++nf) { RD_B(b0[nf], nf, 0); RD_B(b1[nf], nf, 1); }
    if (T + 1 < NT) STG_A(T + 1);
#pragma unroll
    for (int mf = 0; mf < 4; ++mf)
#pragma unroll
      for (int nf = 0; nf < 4; ++nf) {
        acc[mf][nf] = __builtin_amdgcn_mfma_f32_16x16x32_bf16(a0[mf], b0[nf], acc[mf][nf], 0, 0, 0);
        acc[mf][nf] = __builtin_amdgcn_mfma_f32_16x16x32_bf16(a1[mf], b1[nf], acc[mf][nf], 0, 0, 0);
      }
    // ---- mid barrier: every wave's B(T) reads are consumed -> B buffer freed
    BARC();
    // ---- ph2: read A mf4-7; stage B(T+2) into the freed B half; 32 MFMA
#pragma unroll
    for (int mf = 0; mf < 4; ++mf) { RD_A(a0[mf], mf + 4, 0); RD_A(a1[mf], mf + 4, 1); }
    if (T + 2 < NT) STG_B(T + 2);
#pragma unroll
    for (int mf = 0; mf < 4; ++mf)
#pragma unroll
      for (int nf = 0; nf < 4; ++nf) {
        acc[mf+4][nf] = __builtin_amdgcn_mfma_f32_16x16x32_bf16(a0[mf], b0[nf], acc[mf+4][nf], 0, 0, 0);
        acc[mf+4][nf] = __builtin_amdgcn_mfma_f32_16x16x32_bf16(a1[mf], b1[nf], acc[mf+4][nf], 0, 0, 0);
      }
  }
#undef STG_A
#undef STG_B
#undef RD_A
#undef RD_B

#pragma unroll
  for (int mf = 0; mf < 8; ++mf)
#pragma unroll
    for (int nf = 0; nf < 4; ++nf)
#pragma unroll
      for (int j = 0; j < 4; ++j) {
        int m = bm*256 + wr*128 + mf*16 + lg*4 + j;
        int n = bn*256 + wc*64 + nf*16 + lr;
        float v = acc[mf][nf][j];
        if (BF16OUT) ((u16*)Cp)[(size_t)m * N + n] = f2bf(v);
        else         ((float*)Cp)[(size_t)m * N + n] = v;
      }
}

// ---------------- 128x128 B^T GEMM, BK=64 dbuf, 1 barrier/K-tile, 2 blocks/CU ----------------
template<int BF16OUT>
__global__ __launch_bounds__(256, 2) void gemm_bt(const u16* __restrict__ A, const u16* __restrict__ Bw,
                                                  void* __restrict__ Cp, int M, int N, int K) {
  __shared__ __align__(16) u16 lds_[32768];   // 64 KB
  char* ldsb = (char*)lds_;
  const int tid = threadIdx.x;
  const int w = tid >> 6, l = tid & 63;
  const int lr = l & 15, lg = l >> 4;
  const int nwg = (int)(gridDim.x * gridDim.y);
  const int bid = (int)(blockIdx.y * gridDim.x + blockIdx.x);
  const int swz = (bid & 7) * (nwg >> 3) + (bid >> 3);
  const int bm = swz / (int)gridDim.x, bn = swz % (int)gridDim.x;
  const int wr = w >> 1, wc = w & 1;

  f32x4 acc[4][4] = {};

  int row4[4], col4[4];
#pragma unroll
  for (int i = 0; i < 4; ++i) {
    int off = i*4096 + tid*16;
    row4[i] = off >> 7;
    col4[i] = (off & 127) ^ ((row4[i] & 7) << 4);
  }
  const size_t rs = (size_t)K * 2;
  const char* Ab = (const char*)A + (size_t)bm * 128 * rs;
  const char* Bb = (const char*)Bw + (size_t)bn * 128 * rs;
  const int wb = w * 1024;

#define STG(T_) do { \
    char* dA_ = ldsb + ((T_)&1)*16384; \
    char* dB_ = ldsb + 32768 + ((T_)&1)*16384; \
    _Pragma("unroll") \
    for (int i_ = 0; i_ < 4; ++i_) \
      gload_lds16(Ab + (size_t)row4[i_]*rs + (size_t)(T_)*128 + col4[i_], dA_ + i_*4096 + wb); \
    _Pragma("unroll") \
    for (int i_ = 0; i_ < 4; ++i_) \
      gload_lds16(Bb + (size_t)row4[i_]*rs + (size_t)(T_)*128 + col4[i_], dB_ + i_*4096 + wb); \
  } while (0)

  const int NT = K >> 6;
  STG(0);
  TILE_SYNC();

  for (int T = 0; T < NT; ++T) {
    const char* La = ldsb + (T & 1)*16384;
    const char* Lb = ldsb + 32768 + (T & 1)*16384;
    if (T + 1 < NT) STG(T + 1);

    bf16x8 af[4][2], bf[4][2];
#pragma unroll
    for (int mt = 0; mt < 4; ++mt) {
      int row = wr*64 + mt*16 + lr;
#pragma unroll
      for (int ks = 0; ks < 2; ++ks)
        af[mt][ks] = *(const bf16x8*)(La + row*128 + ((ks*64 + lg*16) ^ ((row & 7) << 4)));
    }
#pragma unroll
    for (int nt = 0; nt < 4; ++nt) {
      int row = wc*64 + nt*16 + lr;
#pragma unroll
      for (int ks = 0; ks < 2; ++ks)
        bf[nt][ks] = *(const bf16x8*)(Lb + row*128 + ((ks*64 + lg*16) ^ ((row & 7) << 4)));
    }
#pragma unroll
    for (int mt = 0; mt < 4; ++mt)
#pragma unroll
      for (int nt = 0; nt < 4; ++nt) {
        acc[mt][nt] = __builtin_amdgcn_mfma_f32_16x16x32_bf16(af[mt][0], bf[nt][0], acc[mt][nt], 0, 0, 0);
        acc[mt][nt] = __builtin_amdgcn_mfma_f32_16x16x32_bf16(af[mt][1], bf[nt][1], acc[mt][nt], 0, 0, 0);
      }
    TILE_SYNC();
  }
#undef STG

#pragma unroll
  for (int mt = 0; mt < 4; ++mt)
#pragma unroll
    for (int nt = 0; nt < 4; ++nt)
#pragma unroll
      for (int j = 0; j < 4; ++j) {
        int m = bm*128 + wr*64 + mt*16 + lg*4 + j;
        int n = bn*128 + wc*64 + nt*16 + lr;
        float v = acc[mt][nt][j];
        if (BF16OUT) ((u16*)Cp)[(size_t)m * N + n] = f2bf(v);
        else         ((float*)Cp)[(size_t)m * N + n] = v;
      }
}

// ---------------- RoPE + per-head L2 norm (+attn_scale*log2e on Q) ----------------
__global__ __launch_bounds__(256) void rope_norm(const u16* __restrict__ qkv, const float* __restrict__ fc,
                                                 const float* __restrict__ scale_p,
                                                 u16* __restrict__ Qo, u16* __restrict__ Ko) {
  int gid = blockIdx.x;
  int bs = gid >> 2;
  int s = bs & (S_ - 1);
  int b = bs >> 11;
  int w = threadIdx.x >> 6, l = threadIdx.x & 63;
  int h = (gid & 3)*4 + w;
  float2 cs = ((const float2*)fc)[(size_t)s*64 + l];
  float scale = scale_p[0] * 1.4426950408889634f;  // fold log2(e) for exp2 softmax
  const u16* base = qkv + (size_t)bs * D3_;
  size_t obase = ((size_t)(b*H_ + h) * S_ + s) * HD_ + 2*l;
  {
    const u16* p = base + h*HD_ + 2*l;
    float x0 = bf2f(p[0]), x1 = bf2f(p[1]);
    float r0 = x0*cs.x - x1*cs.y;
    float r1 = x1*cs.x + x0*cs.y;
    float t = r0*r0 + r1*r1;
#pragma unroll
    for (int mk = 1; mk < 64; mk <<= 1) t += __shfl_xor(t, mk, 64);
    float inv = scale / (sqrtf(t) + 1e-6f);
    u16x2 o; o[0] = f2bf(r0*inv); o[1] = f2bf(r1*inv);
    *(u16x2*)(Qo + obase) = o;
  }
  {
    const u16* p = base + D_ + h*HD_ + 2*l;
    float x0 = bf2f(p[0]), x1 = bf2f(p[1]);
    float r0 = x0*cs.x - x1*cs.y;
    float r1 = x1*cs.x + x0*cs.y;
    float t = r0*r0 + r1*r1;
#pragma unroll
    for (int mk = 1; mk < 64; mk <<= 1) t += __shfl_xor(t, mk, 64);
    float inv = 1.0f / (sqrtf(t) + 1e-6f);
    u16x2 o; o[0] = f2bf(r0*inv); o[1] = f2bf(r1*inv);
    *(u16x2*)(Ko + obase) = o;
  }
}

// ---------------- V transpose: qkv v-slice [B,S,H,HD] -> Vt [B*H, HD, S] ----------------
__global__ __launch_bounds__(256) void v_trans(const u16* __restrict__ qkv, u16* __restrict__ Vt) {
  __shared__ u16 vt[64][136];
  int blk = blockIdx.x;
  int bh = blk >> 5, st = blk & 31;
  int b = bh >> 4, h = bh & 15;
  int s0 = st * 64;
  int tid = threadIdx.x;
#pragma unroll
  for (int i = 0; i < 4; ++i) {
    int idx = tid + i*256;
    int row = idx >> 4, ch = idx & 15;
    u16x8 v = *(const u16x8*)(qkv + (size_t)(b*S_ + s0 + row) * D3_ + 2*D_ + h*HD_ + ch*8);
    *(u16x8*)(&vt[row][ch*8]) = v;
  }
  __syncthreads();
#pragma unroll
  for (int p = 0; p < 2; ++p) {
    int d = p*64 + (tid >> 2);
    int q = (tid & 3) * 16;
    u16x8 t0, t1;
#pragma unroll
    for (int i = 0; i < 8; ++i) t0[i] = vt[q + i][d];
#pragma unroll
    for (int i = 0; i < 8; ++i) t1[i] = vt[q + 8 + i][d];
    u16* dst = Vt + ((size_t)bh * HD_ + d) * S_ + s0 + q;
    *(u16x8*)dst = t0;
    *(u16x8*)(dst + 8) = t1;
  }
}

// ---------------- causal flash attention (R10 structure + defer-max T13) ----------------
// QBLK=128, 8 waves (512 thr), KBLK=64. Swapped QK^T, lane-local softmax.
// K dbuf, V single-buf, counted vmcnt(2). Defer-max: skip oacc rescale when
// per-tile max growth <= 8 (log2 domain); P bounded by 2^8.
__global__ __launch_bounds__(512) void flash_attn(const u16* __restrict__ Qh, const u16* __restrict__ Kh,
                                                  const u16* __restrict__ Vt, u16* __restrict__ AO) {
  __shared__ __align__(16) u16 lK[2][64*128];   // 32 KB
  __shared__ __align__(16) u16 lV[128*64];      // 16 KB
  __shared__ __align__(16) u16 lP[8][16*72];    // 18 KB
  const int i0 = (int)blockIdx.x;               // 0..511
  const int k5 = i0 & 255;
  const int bh = k5 >> 3;
  const int jj = k5 & 7;
  const int qt = (i0 < 256) ? (15 - jj) : jj;   // heavy half first
  const int tid = threadIdx.x, w = tid >> 6, l = tid & 63;
  const int lr = l & 15, lg = l >> 4;
  const int b = bh >> 4, h = bh & 15;

  bf16x8 qf[4];
  {
    const u16* qp = Qh + ((size_t)bh * S_ + qt*128 + w*16 + lr) * HD_ + lg*8;
#pragma unroll
    for (int ks = 0; ks < 4; ++ks) qf[ks] = *(const bf16x8*)(qp + ks*32);
  }
  float m0 = -__builtin_inff(), ls0 = 0.f;      // running max/sum for q = w*16 + lr
  f32x4 oacc[8] = {};

  int krow[2], kcol[2], vrow[2], vcol[2], dstb[2];
#pragma unroll
  for (int p = 0; p < 2; ++p) {
    int off = p*8192 + tid*16;
    krow[p] = off >> 8; kcol[p] = (off & 255) ^ ((krow[p] & 7) << 4);
    vrow[p] = off >> 7; vcol[p] = (off & 127) ^ ((vrow[p] & 7) << 4);
    dstb[p] = p*8192 + w*1024;
  }
  const char* Kb = (const char*)(Kh + (size_t)bh * S_ * HD_);
  const char* Vb = (const char*)(Vt + (size_t)bh * HD_ * S_);

#define STAGE_K(nb, kt_) do {                                                       \
    _Pragma("unroll")                                                               \
    for (int p_ = 0; p_ < 2; ++p_)                                                  \
      gload_lds16(Kb + (size_t)((kt_)*64 + krow[p_])*256 + kcol[p_],                \
                  (char*)lK[nb] + dstb[p_]);                                        \
  } while (0)
#define STAGE_V(kt_) do {                                                           \
    _Pragma("unroll")                                                               \
    for (int p_ = 0; p_ < 2; ++p_)                                                  \
      gload_lds16(Vb + (size_t)vrow[p_]*(S_*2) + (kt_)*128 + vcol[p_],              \
                  (char*)lV + dstb[p_]);                                            \
  } while (0)

  const int nt = 2*qt + 2;
  STAGE_K(0, 0);
  STAGE_V(0);
  int cur = 0;
  for (int kt = 0; kt < nt; ++kt) {
    asm volatile("s_waitcnt vmcnt(2)" ::: "memory");
    __builtin_amdgcn_s_barrier();
    asm volatile("" ::: "memory");
    const char* lKb = (const char*)lK[cur];

    // swapped QK^T: sc[f][j] = S[k = kt*64 + f*16 + lg*4 + j][q = qt*128 + w*16 + lr]
    f32x4 sc[4] = {};
    __builtin_amdgcn_s_setprio(1);
#pragma unroll
    for (int ks = 0; ks < 4; ++ks) {
#pragma unroll
      for (int f = 0; f < 4; ++f) {
        int row = f*16 + lr;
        bf16x8 kf = *(const bf16x8*)(lKb + row*256 + ((ks*64 + lg*16) ^ ((row & 7) << 4)));
        sc[f] = __builtin_amdgcn_mfma_f32_16x16x32_bf16(kf, qf[ks], sc[f], 0, 0, 0);
      }
    }
    __builtin_amdgcn_s_setprio(0);
    if (kt < nt-1) STAGE_K(cur ^ 1, kt + 1);   // prefetch next K under softmax

    if (kt >= nt-2) {  // diagonal tiles: mask k > q
#pragma unroll
      for (int f = 0; f < 4; ++f)
#pragma unroll
        for (int j = 0; j < 4; ++j)
          if (kt*64 + f*16 + lg*4 + j > qt*128 + w*16 + lr) sc[f][j] = -__builtin_inff();
    }
    // lane-local online softmax with defer-max
    float pmax = sc[0][0];
#pragma unroll
    for (int f = 0; f < 4; ++f)
#pragma unroll
      for (int j = 0; j < 4; ++j) pmax = fmaxf(pmax, sc[f][j]);
    pmax = fmaxf(pmax, __shfl_xor(pmax, 16, 64));
    pmax = fmaxf(pmax, __shfl_xor(pmax, 32, 64));
    const int norescale = __all(pmax - m0 <= 8.0f);
    float mn;
    float resc = 0.f;
    if (norescale) {
      mn = m0;                       // keep old max; P bounded by 2^8
    } else {
      mn = fmaxf(m0, pmax);
      resc = exp2f(m0 - mn);
      m0 = mn;
    }
    float rsum = 0.f;
#pragma unroll
    for (int f = 0; f < 4; ++f)
#pragma unroll
      for (int j = 0; j < 4; ++j) {
        float p = exp2f(sc[f][j] - mn);
        sc[f][j] = p;
        rsum += p;
      }
    rsum += __shfl_xor(rsum, 16, 64);
    rsum += __shfl_xor(rsum, 32, 64);
    if (norescale) {
      ls0 = ls0 + rsum;
    } else {
      ls0 = ls0 * resc + rsum;
      // redistribute resc from lr-space to j-space (q = w*16 + lg*4 + j)
      float rescj[4];
#pragma unroll
      for (int j = 0; j < 4; ++j) rescj[j] = __shfl(resc, lg*4 + j, 64);
#pragma unroll
      for (int fd = 0; fd < 8; ++fd)
#pragma unroll
        for (int j = 0; j < 4; ++j) oacc[fd][j] *= rescj[j];
    }
    // P[q=lr][k] packed write: one b64 per f
#pragma unroll
    for (int f = 0; f < 4; ++f) {
      u16x4 pk;
#pragma unroll
      for (int j = 0; j < 4; ++j) pk[j] = f2bf(sc[f][j]);
      *(u16x4*)((char*)lP[w] + lr*144 + f*32 + lg*8) = pk;
    }

    if (kt < nt-1) { asm volatile("s_waitcnt vmcnt(2)" ::: "memory"); }
    else           { asm volatile("s_waitcnt vmcnt(0)" ::: "memory"); }
    __builtin_amdgcn_s_barrier();
    asm volatile("" ::: "memory");
    // PV: oacc[fd] j-space rows q = w*16 + lg*4 + j
    __builtin_amdgcn_s_setprio(1);
#pragma unroll
    for (int ks = 0; ks < 2; ++ks) {
      bf16x8 pf = *(const bf16x8*)((const char*)lP[w] + lr*144 + ks*64 + lg*16);
#pragma unroll
      for (int fd = 0; fd < 8; ++fd) {
        int row = fd*16 + lr;
        bf16x8 vf = *(const bf16x8*)((const char*)lV + row*128 + ((ks*64 + lg*16) ^ ((row & 7) << 4)));
        oacc[fd] = __builtin_amdgcn_mfma_f32_16x16x32_bf16(pf, vf, oacc[fd], 0, 0, 0);
      }
    }
    __builtin_amdgcn_s_setprio(0);
    asm volatile("" ::: "memory");
    __builtin_amdgcn_s_barrier();
    asm volatile("" ::: "memory");
    if (kt < nt-1) STAGE_V(kt + 1);
    cur ^= 1;
  }
#undef STAGE_K
#undef STAGE_V
  // epilogue: 1/ls redistributed to j-space
  float invl[4];
#pragma unroll
  for (int j = 0; j < 4; ++j) {
    float lsj = __shfl(ls0, lg*4 + j, 64);
    invl[j] = 1.0f / lsj;
  }
#pragma unroll
  for (int fd = 0; fd < 8; ++fd)
#pragma unroll
    for (int j = 0; j < 4; ++j) {
      int qq = qt*128 + w*16 + lg*4 + j;
      int dd = fd*16 + lr;
      float v = oacc[fd][j] * invl[j];
      AO[((size_t)b*S_ + qq)*D_ + h*HD_ + dd] = f2bf(v);
    }
}

// ---------------- launch ----------------
extern "C" void kernel_launch(void* const* d_in, const int* in_sizes, int n_in,
                              void* d_out, int out_size, void* d_ws, size_t ws_size,
                              hipStream_t stream) {
  const float* x        = (const float*)d_in[0];
  const float* w_qkv    = (const float*)d_in[1];
  const float* w_out    = (const float*)d_in[2];
  const float* attn_sc  = (const float*)d_in[3];
  const float* freqs    = (const float*)d_in[4];

  if (ws_size < 167772160u) return;  // need 160 MB scratch

  char* ws = (char*)d_ws;
  u16* xbf  = (u16*)(ws);                 //  16 MB  [4096][2048]
  u16* wqbf = (u16*)(ws + 16777216);      //  24 MB  [6144][2048]
  u16* wobf = (u16*)(ws + 41943040);      //   8 MB  [2048][2048]
  u16* qkv  = (u16*)(ws + 50331648);      //  48 MB  [4096][6144]
  u16* Qh   = (u16*)(ws + 100663296);     //  16 MB  [B*H][S][HD]
  u16* Kh   = (u16*)(ws + 117440512);     //  16 MB  [B*H][S][HD]
  u16* Vt   = (u16*)(ws + 134217728);     //  16 MB  [B*H][HD][S]
  u16* AO   = (u16*)(ws + 150994944);     //  16 MB  [4096][2048]

  castk<<<4096, 256, 0, stream>>>(x,     xbf,  8388608);
  castk<<<6144, 256, 0, stream>>>(w_qkv, wqbf, 12582912);
  castk<<<2048, 256, 0, stream>>>(w_out, wobf, 4194304);

  // QKV: 256x256 tiles -> (24, 16) = 384 blocks
  gemm8<1><<<dim3(24, 16), 512, 0, stream>>>(xbf, wqbf, qkv, 4096, 6144, 2048);

  rope_norm<<<16384, 256, 0, stream>>>(qkv, freqs, attn_sc, Qh, Kh);
  v_trans<<<1024, 256, 0, stream>>>(qkv, Vt);

  flash_attn<<<512, 512, 0, stream>>>(Qh, Kh, Vt, AO);

  // out-projection: 128x128 tiles, (16, 32) = 512 blocks, 2 blocks/CU
  gemm_bt<0><<<dim3(16, 32), 256, 0, stream>>>(AO, wobf, (float*)d_out, 4096, 2048, 2048);
}

// Round 13
// 251.345 us; speedup vs baseline: 1.1378x; 1.0805x over previous
//
#include <hip/hip_runtime.h>
#include <stdint.h>

#define B_  2
#define S_  2048
#define D_  2048
#define H_  16
#define HD_ 128
#define D3_ 6144

typedef unsigned short u16;
typedef __attribute__((ext_vector_type(8))) __bf16 bf16x8;
typedef __attribute__((ext_vector_type(4))) float f32x4;
typedef __attribute__((ext_vector_type(8))) u16  u16x8;
typedef __attribute__((ext_vector_type(4))) u16  u16x4;
typedef __attribute__((ext_vector_type(2))) u16  u16x2;

__device__ inline u16 f2bf(float f) {
  union { float f; uint32_t u; } v; v.f = f;
  uint32_t r = v.u + 0x7FFFu + ((v.u >> 16) & 1u);
  return (u16)(r >> 16);
}
__device__ inline float bf2f(u16 u) {
  union { float f; uint32_t u; } v; v.u = ((uint32_t)u) << 16;
  return v.f;
}
__device__ inline void gload_lds16(const void* g, void* l) {
  __builtin_amdgcn_global_load_lds((const __attribute__((address_space(1))) uint32_t*)g,
                                   (__attribute__((address_space(3))) uint32_t*)l, 16, 0, 0);
}

// tile-boundary sync: own ds_reads consumed, own staged gloads landed, barrier.
#define TILE_SYNC() do { \
    asm volatile("s_waitcnt lgkmcnt(0)" ::: "memory"); \
    asm volatile("s_waitcnt vmcnt(0)" ::: "memory"); \
    __builtin_amdgcn_s_barrier(); \
    asm volatile("" ::: "memory"); \
  } while (0)

// ---------------- fused fp32 -> bf16 casts (x, w_qkv, w_out in one launch) ----------------
__global__ __launch_bounds__(256) void castk3(const float* __restrict__ x, const float* __restrict__ wq,
                                              const float* __restrict__ wo,
                                              u16* __restrict__ xo, u16* __restrict__ wqo, u16* __restrict__ woo) {
  int blk = (int)blockIdx.x;
  const float* in; u16* out; int base;
  if (blk < 4096)       { in = x;  out = xo;  base = blk; }
  else if (blk < 10240) { in = wq; out = wqo; base = blk - 4096; }
  else                  { in = wo; out = woo; base = blk - 10240; }
  int i = base * 256 + (int)threadIdx.x;
  f32x4 a = ((const f32x4*)in)[2*i];
  f32x4 b = ((const f32x4*)in)[2*i + 1];
  u16x8 o;
#pragma unroll
  for (int j = 0; j < 4; ++j) o[j] = f2bf(a[j]);
#pragma unroll
  for (int j = 0; j < 4; ++j) o[4+j] = f2bf(b[j]);
  ((u16x8*)out)[i] = o;
}

// ============ B^T GEMM, BM=256, BN=384, BK=32, 8 waves (2M x 4N, wave 128x96).
// Grid (16,16) = 256 blocks = EXACT 1 round of 256 CUs (packing 1.0).
// LDS 80KB: A[2][16KB] | B[2][24KB], 64B rows (BK=32) — naturally conflict-free
// for ds_read_b128 frags (bank period 128B = 2 rows), linear staging, no swizzle.
// R8's proven one-barrier-per-tile structure. reads/MFMA = 14/48 = 0.29. ============
template<int BF16OUT>
__global__ __launch_bounds__(512, 2) void gemm384(const u16* __restrict__ A, const u16* __restrict__ Bw,
                                                  void* __restrict__ Cp, int M, int N, int K) {
  __shared__ __align__(16) u16 lds_[40960];   // 80 KB
  char* ldsb = (char*)lds_;
  const int tid = threadIdx.x;
  const int w = tid >> 6, l = tid & 63;
  const int lr = l & 15, lg = l >> 4;
  const int wr = w >> 2, wc = w & 3;          // 2M x 4N waves
  const int nbn = (int)gridDim.x;
  const int nwg = nbn * (int)gridDim.y;
  const int bid = (int)(blockIdx.y * gridDim.x + blockIdx.x);
  const int swz = (bid & 7) * (nwg >> 3) + (bid >> 3);   // XCD swizzle (nwg%8==0)
  const int bm = swz / nbn, bn = swz % nbn;

  f32x4 acc[8][6] = {};

  // staging maps: chunk off = p*8192 + tid*16; m = off>>6 (64B rows), kb = off&63
  int mA[2], kA[2], mB[3], kB[3];
#pragma unroll
  for (int p = 0; p < 2; ++p) { int off = p*8192 + tid*16; mA[p] = off >> 6; kA[p] = off & 63; }
#pragma unroll
  for (int p = 0; p < 3; ++p) { int off = p*8192 + tid*16; mB[p] = off >> 6; kB[p] = off & 63; }
  const size_t rs = (size_t)K * 2;
  const char* Ab = (const char*)A + (size_t)bm * 256 * rs;
  const char* Bb = (const char*)Bw + (size_t)bn * 384 * rs;
  const int wb = w * 1024;

#define STG(T_) do { \
    char* dA_ = ldsb + ((T_)&1)*16384; \
    char* dB_ = ldsb + 32768 + ((T_)&1)*24576; \
    _Pragma("unroll") \
    for (int p_ = 0; p_ < 2; ++p_) \
      gload_lds16(Ab + (size_t)mA[p_]*rs + (size_t)(T_)*64 + kA[p_], dA_ + p_*8192 + wb); \
    _Pragma("unroll") \
    for (int p_ = 0; p_ < 3; ++p_) \
      gload_lds16(Bb + (size_t)mB[p_]*rs + (size_t)(T_)*64 + kB[p_], dB_ + p_*8192 + wb); \
  } while (0)

  const int NT = K >> 5;   // BK=32
  STG(0);
  TILE_SYNC();

  for (int T = 0; T < NT; ++T) {
    const char* La = ldsb + (T & 1)*16384;
    const char* Lb = ldsb + 32768 + (T & 1)*24576;
    if (T + 1 < NT) STG(T + 1);          // 5 gloads into the inactive buffer

    bf16x8 bfr[6];
#pragma unroll
    for (int nf = 0; nf < 6; ++nf) {
      int row = wc*96 + nf*16 + lr;
      bfr[nf] = *(const bf16x8*)(Lb + row*64 + lg*16);
    }
#pragma unroll
    for (int mf = 0; mf < 8; ++mf) {
      int row = wr*128 + mf*16 + lr;
      bf16x8 af = *(const bf16x8*)(La + row*64 + lg*16);
#pragma unroll
      for (int nf = 0; nf < 6; ++nf)
        acc[mf][nf] = __builtin_amdgcn_mfma_f32_16x16x32_bf16(af, bfr[nf], acc[mf][nf], 0, 0, 0);
    }
    TILE_SYNC();
  }
#undef STG

#pragma unroll
  for (int mf = 0; mf < 8; ++mf)
#pragma unroll
    for (int nf = 0; nf < 6; ++nf)
#pragma unroll
      for (int j = 0; j < 4; ++j) {
        int m = bm*256 + wr*128 + mf*16 + lg*4 + j;
        int n = bn*384 + wc*96 + nf*16 + lr;
        float v = acc[mf][nf][j];
        if (BF16OUT) ((u16*)Cp)[(size_t)m * N + n] = f2bf(v);
        else         ((float*)Cp)[(size_t)m * N + n] = v;
      }
}

// ---------------- 128x128 B^T GEMM, BK=64 dbuf, 1 barrier/K-tile, 2 blocks/CU ----------------
template<int BF16OUT>
__global__ __launch_bounds__(256, 2) void gemm_bt(const u16* __restrict__ A, const u16* __restrict__ Bw,
                                                  void* __restrict__ Cp, int M, int N, int K) {
  __shared__ __align__(16) u16 lds_[32768];   // 64 KB
  char* ldsb = (char*)lds_;
  const int tid = threadIdx.x;
  const int w = tid >> 6, l = tid & 63;
  const int lr = l & 15, lg = l >> 4;
  const int nwg = (int)(gridDim.x * gridDim.y);
  const int bid = (int)(blockIdx.y * gridDim.x + blockIdx.x);
  const int swz = (bid & 7) * (nwg >> 3) + (bid >> 3);
  const int bm = swz / (int)gridDim.x, bn = swz % (int)gridDim.x;
  const int wr = w >> 1, wc = w & 1;

  f32x4 acc[4][4] = {};

  int row4[4], col4[4];
#pragma unroll
  for (int i = 0; i < 4; ++i) {
    int off = i*4096 + tid*16;
    row4[i] = off >> 7;
    col4[i] = (off & 127) ^ ((row4[i] & 7) << 4);
  }
  const size_t rs = (size_t)K * 2;
  const char* Ab = (const char*)A + (size_t)bm * 128 * rs;
  const char* Bb = (const char*)Bw + (size_t)bn * 128 * rs;
  const int wb = w * 1024;

#define STG(T_) do { \
    char* dA_ = ldsb + ((T_)&1)*16384; \
    char* dB_ = ldsb + 32768 + ((T_)&1)*16384; \
    _Pragma("unroll") \
    for (int i_ = 0; i_ < 4; ++i_) \
      gload_lds16(Ab + (size_t)row4[i_]*rs + (size_t)(T_)*128 + col4[i_], dA_ + i_*4096 + wb); \
    _Pragma("unroll") \
    for (int i_ = 0; i_ < 4; ++i_) \
      gload_lds16(Bb + (size_t)row4[i_]*rs + (size_t)(T_)*128 + col4[i_], dB_ + i_*4096 + wb); \
  } while (0)

  const int NT = K >> 6;
  STG(0);
  TILE_SYNC();

  for (int T = 0; T < NT; ++T) {
    const char* La = ldsb + (T & 1)*16384;
    const char* Lb = ldsb + 32768 + (T & 1)*16384;
    if (T + 1 < NT) STG(T + 1);

    bf16x8 af[4][2], bf[4][2];
#pragma unroll
    for (int mt = 0; mt < 4; ++mt) {
      int row = wr*64 + mt*16 + lr;
#pragma unroll
      for (int ks = 0; ks < 2; ++ks)
        af[mt][ks] = *(const bf16x8*)(La + row*128 + ((ks*64 + lg*16) ^ ((row & 7) << 4)));
    }
#pragma unroll
    for (int nt = 0; nt < 4; ++nt) {
      int row = wc*64 + nt*16 + lr;
#pragma unroll
      for (int ks = 0; ks < 2; ++ks)
        bf[nt][ks] = *(const bf16x8*)(Lb + row*128 + ((ks*64 + lg*16) ^ ((row & 7) << 4)));
    }
#pragma unroll
    for (int mt = 0; mt < 4; ++mt)
#pragma unroll
      for (int nt = 0; nt < 4; ++nt) {
        acc[mt][nt] = __builtin_amdgcn_mfma_f32_16x16x32_bf16(af[mt][0], bf[nt][0], acc[mt][nt], 0, 0, 0);
        acc[mt][nt] = __builtin_amdgcn_mfma_f32_16x16x32_bf16(af[mt][1], bf[nt][1], acc[mt][nt], 0, 0, 0);
      }
    TILE_SYNC();
  }
#undef STG

#pragma unroll
  for (int mt = 0; mt < 4; ++mt)
#pragma unroll
    for (int nt = 0; nt < 4; ++nt)
#pragma unroll
      for (int j = 0; j < 4; ++j) {
        int m = bm*128 + wr*64 + mt*16 + lg*4 + j;
        int n = bn*128 + wc*64 + nt*16 + lr;
        float v = acc[mt][nt][j];
        if (BF16OUT) ((u16*)Cp)[(size_t)m * N + n] = f2bf(v);
        else         ((float*)Cp)[(size_t)m * N + n] = v;
      }
}

// ---------------- RoPE + per-head L2 norm (+attn_scale*log2e on Q) ----------------
__global__ __launch_bounds__(256) void rope_norm(const u16* __restrict__ qkv, const float* __restrict__ fc,
                                                 const float* __restrict__ scale_p,
                                                 u16* __restrict__ Qo, u16* __restrict__ Ko) {
  int gid = blockIdx.x;
  int bs = gid >> 2;
  int s = bs & (S_ - 1);
  int b = bs >> 11;
  int w = threadIdx.x >> 6, l = threadIdx.x & 63;
  int h = (gid & 3)*4 + w;
  float2 cs = ((const float2*)fc)[(size_t)s*64 + l];
  float scale = scale_p[0] * 1.4426950408889634f;  // fold log2(e) for exp2 softmax
  const u16* base = qkv + (size_t)bs * D3_;
  size_t obase = ((size_t)(b*H_ + h) * S_ + s) * HD_ + 2*l;
  {
    const u16* p = base + h*HD_ + 2*l;
    float x0 = bf2f(p[0]), x1 = bf2f(p[1]);
    float r0 = x0*cs.x - x1*cs.y;
    float r1 = x1*cs.x + x0*cs.y;
    float t = r0*r0 + r1*r1;
#pragma unroll
    for (int mk = 1; mk < 64; mk <<= 1) t += __shfl_xor(t, mk, 64);
    float inv = scale / (sqrtf(t) + 1e-6f);
    u16x2 o; o[0] = f2bf(r0*inv); o[1] = f2bf(r1*inv);
    *(u16x2*)(Qo + obase) = o;
  }
  {
    const u16* p = base + D_ + h*HD_ + 2*l;
    float x0 = bf2f(p[0]), x1 = bf2f(p[1]);
    float r0 = x0*cs.x - x1*cs.y;
    float r1 = x1*cs.x + x0*cs.y;
    float t = r0*r0 + r1*r1;
#pragma unroll
    for (int mk = 1; mk < 64; mk <<= 1) t += __shfl_xor(t, mk, 64);
    float inv = 1.0f / (sqrtf(t) + 1e-6f);
    u16x2 o; o[0] = f2bf(r0*inv); o[1] = f2bf(r1*inv);
    *(u16x2*)(Ko + obase) = o;
  }
}

// ---------------- V transpose: qkv v-slice [B,S,H,HD] -> Vt [B*H, HD, S] ----------------
__global__ __launch_bounds__(256) void v_trans(const u16* __restrict__ qkv, u16* __restrict__ Vt) {
  __shared__ u16 vt[64][136];
  int blk = blockIdx.x;
  int bh = blk >> 5, st = blk & 31;
  int b = bh >> 4, h = bh & 15;
  int s0 = st * 64;
  int tid = threadIdx.x;
#pragma unroll
  for (int i = 0; i < 4; ++i) {
    int idx = tid + i*256;
    int row = idx >> 4, ch = idx & 15;
    u16x8 v = *(const u16x8*)(qkv + (size_t)(b*S_ + s0 + row) * D3_ + 2*D_ + h*HD_ + ch*8);
    *(u16x8*)(&vt[row][ch*8]) = v;
  }
  __syncthreads();
#pragma unroll
  for (int p = 0; p < 2; ++p) {
    int d = p*64 + (tid >> 2);
    int q = (tid & 3) * 16;
    u16x8 t0, t1;
#pragma unroll
    for (int i = 0; i < 8; ++i) t0[i] = vt[q + i][d];
#pragma unroll
    for (int i = 0; i < 8; ++i) t1[i] = vt[q + 8 + i][d];
    u16* dst = Vt + ((size_t)bh * HD_ + d) * S_ + s0 + q;
    *(u16x8*)dst = t0;
    *(u16x8*)(dst + 8) = t1;
  }
}

// ---------------- causal flash attention (swapped QK^T, lane-local softmax, defer-max) ----------------
__global__ __launch_bounds__(512) void flash_attn(const u16* __restrict__ Qh, const u16* __restrict__ Kh,
                                                  const u16* __restrict__ Vt, u16* __restrict__ AO) {
  __shared__ __align__(16) u16 lK[2][64*128];   // 32 KB
  __shared__ __align__(16) u16 lV[128*64];      // 16 KB
  __shared__ __align__(16) u16 lP[8][16*72];    // 18 KB
  const int i0 = (int)blockIdx.x;               // 0..511
  const int k5 = i0 & 255;
  const int bh = k5 >> 3;
  const int jj = k5 & 7;
  const int qt = (i0 < 256) ? (15 - jj) : jj;   // heavy half first
  const int tid = threadIdx.x, w = tid >> 6, l = tid & 63;
  const int lr = l & 15, lg = l >> 4;
  const int b = bh >> 4, h = bh & 15;

  bf16x8 qf[4];
  {
    const u16* qp = Qh + ((size_t)bh * S_ + qt*128 + w*16 + lr) * HD_ + lg*8;
#pragma unroll
    for (int ks = 0; ks < 4; ++ks) qf[ks] = *(const bf16x8*)(qp + ks*32);
  }
  float m0 = -__builtin_inff(), ls0 = 0.f;      // running max/sum for q = w*16 + lr
  f32x4 oacc[8] = {};

  int krow[2], kcol[2], vrow[2], vcol[2], dstb[2];
#pragma unroll
  for (int p = 0; p < 2; ++p) {
    int off = p*8192 + tid*16;
    krow[p] = off >> 8; kcol[p] = (off & 255) ^ ((krow[p] & 7) << 4);
    vrow[p] = off >> 7; vcol[p] = (off & 127) ^ ((vrow[p] & 7) << 4);
    dstb[p] = p*8192 + w*1024;
  }
  const char* Kb = (const char*)(Kh + (size_t)bh * S_ * HD_);
  const char* Vb = (const char*)(Vt + (size_t)bh * HD_ * S_);

#define STAGE_K(nb, kt_) do {                                                       \
    _Pragma("unroll")                                                               \
    for (int p_ = 0; p_ < 2; ++p_)                                                  \
      gload_lds16(Kb + (size_t)((kt_)*64 + krow[p_])*256 + kcol[p_],                \
                  (char*)lK[nb] + dstb[p_]);                                        \
  } while (0)
#define STAGE_V(kt_) do {                                                           \
    _Pragma("unroll")                                                               \
    for (int p_ = 0; p_ < 2; ++p_)                                                  \
      gload_lds16(Vb + (size_t)vrow[p_]*(S_*2) + (kt_)*128 + vcol[p_],              \
                  (char*)lV + dstb[p_]);                                            \
  } while (0)

  const int nt = 2*qt + 2;
  STAGE_K(0, 0);
  STAGE_V(0);
  int cur = 0;
  for (int kt = 0; kt < nt; ++kt) {
    asm volatile("s_waitcnt vmcnt(2)" ::: "memory");
    __builtin_amdgcn_s_barrier();
    asm volatile("" ::: "memory");
    const char* lKb = (const char*)lK[cur];

    // swapped QK^T: sc[f][j] = S[k = kt*64 + f*16 + lg*4 + j][q = qt*128 + w*16 + lr]
    f32x4 sc[4] = {};
    __builtin_amdgcn_s_setprio(1);
#pragma unroll
    for (int ks = 0; ks < 4; ++ks) {
#pragma unroll
      for (int f = 0; f < 4; ++f) {
        int row = f*16 + lr;
        bf16x8 kf = *(const bf16x8*)(lKb + row*256 + ((ks*64 + lg*16) ^ ((row & 7) << 4)));
        sc[f] = __builtin_amdgcn_mfma_f32_16x16x32_bf16(kf, qf[ks], sc[f], 0, 0, 0);
      }
    }
    __builtin_amdgcn_s_setprio(0);
    if (kt < nt-1) STAGE_K(cur ^ 1, kt + 1);   // prefetch next K under softmax

    if (kt >= nt-2) {  // diagonal tiles: mask k > q
#pragma unroll
      for (int f = 0; f < 4; ++f)
#pragma unroll
        for (int j = 0; j < 4; ++j)
          if (kt*64 + f*16 + lg*4 + j > qt*128 + w*16 + lr) sc[f][j] = -__builtin_inff();
    }
    // lane-local online softmax with defer-max
    float pmax = sc[0][0];
#pragma unroll
    for (int f = 0; f < 4; ++f)
#pragma unroll
      for (int j = 0; j < 4; ++j) pmax = fmaxf(pmax, sc[f][j]);
    pmax = fmaxf(pmax, __shfl_xor(pmax, 16, 64));
    pmax = fmaxf(pmax, __shfl_xor(pmax, 32, 64));
    const int norescale = __all(pmax - m0 <= 8.0f);
    float mn;
    float resc = 0.f;
    if (norescale) {
      mn = m0;                       // keep old max; P bounded by 2^8
    } else {
      mn = fmaxf(m0, pmax);
      resc = exp2f(m0 - mn);
      m0 = mn;
    }
    float rsum = 0.f;
#pragma unroll
    for (int f = 0; f < 4; ++f)
#pragma unroll
      for (int j = 0; j < 4; ++j) {
        float p = exp2f(sc[f][j] - mn);
        sc[f][j] = p;
        rsum += p;
      }
    rsum += __shfl_xor(rsum, 16, 64);
    rsum += __shfl_xor(rsum, 32, 64);
    if (norescale) {
      ls0 = ls0 + rsum;
    } else {
      ls0 = ls0 * resc + rsum;
      float rescj[4];
#pragma unroll
      for (int j = 0; j < 4; ++j) rescj[j] = __shfl(resc, lg*4 + j, 64);
#pragma unroll
      for (int fd = 0; fd < 8; ++fd)
#pragma unroll
        for (int j = 0; j < 4; ++j) oacc[fd][j] *= rescj[j];
    }
    // P[q=lr][k] packed write: one b64 per f
#pragma unroll
    for (int f = 0; f < 4; ++f) {
      u16x4 pk;
#pragma unroll
      for (int j = 0; j < 4; ++j) pk[j] = f2bf(sc[f][j]);
      *(u16x4*)((char*)lP[w] + lr*144 + f*32 + lg*8) = pk;
    }

    if (kt < nt-1) { asm volatile("s_waitcnt vmcnt(2)" ::: "memory"); }
    else           { asm volatile("s_waitcnt vmcnt(0)" ::: "memory"); }
    __builtin_amdgcn_s_barrier();
    asm volatile("" ::: "memory");
    // PV
    __builtin_amdgcn_s_setprio(1);
#pragma unroll
    for (int ks = 0; ks < 2; ++ks) {
      bf16x8 pf = *(const bf16x8*)((const char*)lP[w] + lr*144 + ks*64 + lg*16);
#pragma unroll
      for (int fd = 0; fd < 8; ++fd) {
        int row = fd*16 + lr;
        bf16x8 vf = *(const bf16x8*)((const char*)lV + row*128 + ((ks*64 + lg*16) ^ ((row & 7) << 4)));
        oacc[fd] = __builtin_amdgcn_mfma_f32_16x16x32_bf16(pf, vf, oacc[fd], 0, 0, 0);
      }
    }
    __builtin_amdgcn_s_setprio(0);
    asm volatile("" ::: "memory");
    __builtin_amdgcn_s_barrier();
    asm volatile("" ::: "memory");
    if (kt < nt-1) STAGE_V(kt + 1);
    cur ^= 1;
  }
#undef STAGE_K
#undef STAGE_V
  // epilogue: 1/ls redistributed to j-space
  float invl[4];
#pragma unroll
  for (int j = 0; j < 4; ++j) {
    float lsj = __shfl(ls0, lg*4 + j, 64);
    invl[j] = 1.0f / lsj;
  }
#pragma unroll
  for (int fd = 0; fd < 8; ++fd)
#pragma unroll
    for (int j = 0; j < 4; ++j) {
      int qq = qt*128 + w*16 + lg*4 + j;
      int dd = fd*16 + lr;
      float v = oacc[fd][j] * invl[j];
      AO[((size_t)b*S_ + qq)*D_ + h*HD_ + dd] = f2bf(v);
    }
}

// ---------------- launch ----------------
extern "C" void kernel_launch(void* const* d_in, const int* in_sizes, int n_in,
                              void* d_out, int out_size, void* d_ws, size_t ws_size,
                              hipStream_t stream) {
  const float* x        = (const float*)d_in[0];
  const float* w_qkv    = (const float*)d_in[1];
  const float* w_out    = (const float*)d_in[2];
  const float* attn_sc  = (const float*)d_in[3];
  const float* freqs    = (const float*)d_in[4];

  if (ws_size < 167772160u) return;  // need 160 MB scratch

  char* ws = (char*)d_ws;
  u16* xbf  = (u16*)(ws);                 //  16 MB  [4096][2048]
  u16* wqbf = (u16*)(ws + 16777216);      //  24 MB  [6144][2048]
  u16* wobf = (u16*)(ws + 41943040);      //   8 MB  [2048][2048]
  u16* qkv  = (u16*)(ws + 50331648);      //  48 MB  [4096][6144]
  u16* Qh   = (u16*)(ws + 100663296);     //  16 MB  [B*H][S][HD]
  u16* Kh   = (u16*)(ws + 117440512);     //  16 MB  [B*H][S][HD]
  u16* Vt   = (u16*)(ws + 134217728);     //  16 MB  [B*H][HD][S]
  u16* AO   = (u16*)(ws + 150994944);     //  16 MB  [4096][2048]

  castk3<<<12288, 256, 0, stream>>>(x, w_qkv, w_out, xbf, wqbf, wobf);

  // QKV: 256x384 tiles -> (16, 16) = 256 blocks = exact 1 round
  gemm384<1><<<dim3(16, 16), 512, 0, stream>>>(xbf, wqbf, qkv, 4096, 6144, 2048);

  rope_norm<<<16384, 256, 0, stream>>>(qkv, freqs, attn_sc, Qh, Kh);
  v_trans<<<1024, 256, 0, stream>>>(qkv, Vt);

  flash_attn<<<512, 512, 0, stream>>>(Qh, Kh, Vt, AO);

  // out-projection: 128x128 tiles, (16, 32) = 512 blocks, 2 blocks/CU
  gemm_bt<0><<<dim3(16, 32), 256, 0, stream>>>(AO, wobf, (float*)d_out, 4096, 2048, 2048);
}

// Round 14
// 249.844 us; speedup vs baseline: 1.1446x; 1.0060x over previous
//
#include <hip/hip_runtime.h>
#include <stdint.h>

#define B_  2
#define S_  2048
#define D_  2048
#define H_  16
#define HD_ 128
#define D3_ 6144

typedef unsigned short u16;
typedef __attribute__((ext_vector_type(8))) __bf16 bf16x8;
typedef __attribute__((ext_vector_type(4))) float f32x4;
typedef __attribute__((ext_vector_type(8))) u16  u16x8;
typedef __attribute__((ext_vector_type(4))) u16  u16x4;
typedef __attribute__((ext_vector_type(2))) u16  u16x2;

__device__ inline u16 f2bf(float f) {
  union { float f; uint32_t u; } v; v.f = f;
  uint32_t r = v.u + 0x7FFFu + ((v.u >> 16) & 1u);
  return (u16)(r >> 16);
}
__device__ inline float bf2f(u16 u) {
  union { float f; uint32_t u; } v; v.u = ((uint32_t)u) << 16;
  return v.f;
}
__device__ inline void gload_lds16(const void* g, void* l) {
  __builtin_amdgcn_global_load_lds((const __attribute__((address_space(1))) uint32_t*)g,
                                   (__attribute__((address_space(3))) uint32_t*)l, 16, 0, 0);
}

// tile-boundary sync: own ds_reads consumed, own staged gloads landed, barrier.
#define TILE_SYNC() do { \
    asm volatile("s_waitcnt lgkmcnt(0)" ::: "memory"); \
    asm volatile("s_waitcnt vmcnt(0)" ::: "memory"); \
    __builtin_amdgcn_s_barrier(); \
    asm volatile("" ::: "memory"); \
  } while (0)

// ---------------- fused fp32 -> bf16 casts (x, w_qkv, w_out in one launch) ----------------
__global__ __launch_bounds__(256) void castk3(const float* __restrict__ x, const float* __restrict__ wq,
                                              const float* __restrict__ wo,
                                              u16* __restrict__ xo, u16* __restrict__ wqo, u16* __restrict__ woo) {
  int blk = (int)blockIdx.x;
  const float* in; u16* out; int base;
  if (blk < 4096)       { in = x;  out = xo;  base = blk; }
  else if (blk < 10240) { in = wq; out = wqo; base = blk - 4096; }
  else                  { in = wo; out = woo; base = blk - 10240; }
  int i = base * 256 + (int)threadIdx.x;
  f32x4 a = ((const f32x4*)in)[2*i];
  f32x4 b = ((const f32x4*)in)[2*i + 1];
  u16x8 o;
#pragma unroll
  for (int j = 0; j < 4; ++j) o[j] = f2bf(a[j]);
#pragma unroll
  for (int j = 0; j < 4; ++j) o[4+j] = f2bf(b[j]);
  ((u16x8*)out)[i] = o;
}

// ============ B^T GEMM, BM=256, BN=384, BK=32, 8 waves (2M x 4N, wave 128x96).
// Grid (16,16) = 256 blocks = EXACT 1 round (packing 1.0). LDS 80KB, 64B rows.
// Bank fix (R14): XOR col with ((row>>1)&3)<<4 -> start banks spread over 8
// positions, 2-way max (free). Involution applied on staging SOURCE + read. ============
template<int BF16OUT>
__global__ __launch_bounds__(512, 2) void gemm384(const u16* __restrict__ A, const u16* __restrict__ Bw,
                                                  void* __restrict__ Cp, int M, int N, int K) {
  __shared__ __align__(16) u16 lds_[40960];   // 80 KB
  char* ldsb = (char*)lds_;
  const int tid = threadIdx.x;
  const int w = tid >> 6, l = tid & 63;
  const int lr = l & 15, lg = l >> 4;
  const int wr = w >> 2, wc = w & 3;          // 2M x 4N waves
  const int nbn = (int)gridDim.x;
  const int nwg = nbn * (int)gridDim.y;
  const int bid = (int)(blockIdx.y * gridDim.x + blockIdx.x);
  const int swz = (bid & 7) * (nwg >> 3) + (bid >> 3);   // XCD swizzle (nwg%8==0)
  const int bm = swz / nbn, bn = swz % nbn;

  f32x4 acc[8][6] = {};

  // staging maps: off = p*8192 + tid*16; m = off>>6 (64B rows);
  // source col pre-swizzled: k = (off&63) ^ (((m>>1)&3)<<4)
  int mA[2], kA[2], mB[3], kB[3];
#pragma unroll
  for (int p = 0; p < 2; ++p) {
    int off = p*8192 + tid*16; mA[p] = off >> 6;
    kA[p] = (off & 63) ^ (((mA[p] >> 1) & 3) << 4);
  }
#pragma unroll
  for (int p = 0; p < 3; ++p) {
    int off = p*8192 + tid*16; mB[p] = off >> 6;
    kB[p] = (off & 63) ^ (((mB[p] >> 1) & 3) << 4);
  }
  const size_t rs = (size_t)K * 2;
  const char* Ab = (const char*)A + (size_t)bm * 256 * rs;
  const char* Bb = (const char*)Bw + (size_t)bn * 384 * rs;
  const int wb = w * 1024;

#define STG(T_) do { \
    char* dA_ = ldsb + ((T_)&1)*16384; \
    char* dB_ = ldsb + 32768 + ((T_)&1)*24576; \
    _Pragma("unroll") \
    for (int p_ = 0; p_ < 2; ++p_) \
      gload_lds16(Ab + (size_t)mA[p_]*rs + (size_t)(T_)*64 + kA[p_], dA_ + p_*8192 + wb); \
    _Pragma("unroll") \
    for (int p_ = 0; p_ < 3; ++p_) \
      gload_lds16(Bb + (size_t)mB[p_]*rs + (size_t)(T_)*64 + kB[p_], dB_ + p_*8192 + wb); \
  } while (0)

  const int NT = K >> 5;   // BK=32
  STG(0);
  TILE_SYNC();

  for (int T = 0; T < NT; ++T) {
    const char* La = ldsb + (T & 1)*16384;
    const char* Lb = ldsb + 32768 + (T & 1)*24576;
    if (T + 1 < NT) STG(T + 1);          // 5 gloads into the inactive buffer

    bf16x8 bfr[6];
#pragma unroll
    for (int nf = 0; nf < 6; ++nf) {
      int row = wc*96 + nf*16 + lr;
      bfr[nf] = *(const bf16x8*)(Lb + row*64 + ((lg*16) ^ (((row >> 1) & 3) << 4)));
    }
#pragma unroll
    for (int mf = 0; mf < 8; ++mf) {
      int row = wr*128 + mf*16 + lr;
      bf16x8 af = *(const bf16x8*)(La + row*64 + ((lg*16) ^ (((row >> 1) & 3) << 4)));
#pragma unroll
      for (int nf = 0; nf < 6; ++nf)
        acc[mf][nf] = __builtin_amdgcn_mfma_f32_16x16x32_bf16(af, bfr[nf], acc[mf][nf], 0, 0, 0);
    }
    TILE_SYNC();
  }
#undef STG

#pragma unroll
  for (int mf = 0; mf < 8; ++mf)
#pragma unroll
    for (int nf = 0; nf < 6; ++nf)
#pragma unroll
      for (int j = 0; j < 4; ++j) {
        int m = bm*256 + wr*128 + mf*16 + lg*4 + j;
        int n = bn*384 + wc*96 + nf*16 + lr;
        float v = acc[mf][nf][j];
        if (BF16OUT) ((u16*)Cp)[(size_t)m * N + n] = f2bf(v);
        else         ((float*)Cp)[(size_t)m * N + n] = v;
      }
}

// ---------------- 128x128 B^T GEMM, BK=64 dbuf, 1 barrier/K-tile, 2 blocks/CU ----------------
template<int BF16OUT>
__global__ __launch_bounds__(256, 2) void gemm_bt(const u16* __restrict__ A, const u16* __restrict__ Bw,
                                                  void* __restrict__ Cp, int M, int N, int K) {
  __shared__ __align__(16) u16 lds_[32768];   // 64 KB
  char* ldsb = (char*)lds_;
  const int tid = threadIdx.x;
  const int w = tid >> 6, l = tid & 63;
  const int lr = l & 15, lg = l >> 4;
  const int nwg = (int)(gridDim.x * gridDim.y);
  const int bid = (int)(blockIdx.y * gridDim.x + blockIdx.x);
  const int swz = (bid & 7) * (nwg >> 3) + (bid >> 3);
  const int bm = swz / (int)gridDim.x, bn = swz % (int)gridDim.x;
  const int wr = w >> 1, wc = w & 1;

  f32x4 acc[4][4] = {};

  int row4[4], col4[4];
#pragma unroll
  for (int i = 0; i < 4; ++i) {
    int off = i*4096 + tid*16;
    row4[i] = off >> 7;
    col4[i] = (off & 127) ^ ((row4[i] & 7) << 4);
  }
  const size_t rs = (size_t)K * 2;
  const char* Ab = (const char*)A + (size_t)bm * 128 * rs;
  const char* Bb = (const char*)Bw + (size_t)bn * 128 * rs;
  const int wb = w * 1024;

#define STG(T_) do { \
    char* dA_ = ldsb + ((T_)&1)*16384; \
    char* dB_ = ldsb + 32768 + ((T_)&1)*16384; \
    _Pragma("unroll") \
    for (int i_ = 0; i_ < 4; ++i_) \
      gload_lds16(Ab + (size_t)row4[i_]*rs + (size_t)(T_)*128 + col4[i_], dA_ + i_*4096 + wb); \
    _Pragma("unroll") \
    for (int i_ = 0; i_ < 4; ++i_) \
      gload_lds16(Bb + (size_t)row4[i_]*rs + (size_t)(T_)*128 + col4[i_], dB_ + i_*4096 + wb); \
  } while (0)

  const int NT = K >> 6;
  STG(0);
  TILE_SYNC();

  for (int T = 0; T < NT; ++T) {
    const char* La = ldsb + (T & 1)*16384;
    const char* Lb = ldsb + 32768 + (T & 1)*16384;
    if (T + 1 < NT) STG(T + 1);

    bf16x8 af[4][2], bf[4][2];
#pragma unroll
    for (int mt = 0; mt < 4; ++mt) {
      int row = wr*64 + mt*16 + lr;
#pragma unroll
      for (int ks = 0; ks < 2; ++ks)
        af[mt][ks] = *(const bf16x8*)(La + row*128 + ((ks*64 + lg*16) ^ ((row & 7) << 4)));
    }
#pragma unroll
    for (int nt = 0; nt < 4; ++nt) {
      int row = wc*64 + nt*16 + lr;
#pragma unroll
      for (int ks = 0; ks < 2; ++ks)
        bf[nt][ks] = *(const bf16x8*)(Lb + row*128 + ((ks*64 + lg*16) ^ ((row & 7) << 4)));
    }
#pragma unroll
    for (int mt = 0; mt < 4; ++mt)
#pragma unroll
      for (int nt = 0; nt < 4; ++nt) {
        acc[mt][nt] = __builtin_amdgcn_mfma_f32_16x16x32_bf16(af[mt][0], bf[nt][0], acc[mt][nt], 0, 0, 0);
        acc[mt][nt] = __builtin_amdgcn_mfma_f32_16x16x32_bf16(af[mt][1], bf[nt][1], acc[mt][nt], 0, 0, 0);
      }
    TILE_SYNC();
  }
#undef STG

#pragma unroll
  for (int mt = 0; mt < 4; ++mt)
#pragma unroll
    for (int nt = 0; nt < 4; ++nt)
#pragma unroll
      for (int j = 0; j < 4; ++j) {
        int m = bm*128 + wr*64 + mt*16 + lg*4 + j;
        int n = bn*128 + wc*64 + nt*16 + lr;
        float v = acc[mt][nt][j];
        if (BF16OUT) ((u16*)Cp)[(size_t)m * N + n] = f2bf(v);
        else         ((float*)Cp)[(size_t)m * N + n] = v;
      }
}

// ---------------- RoPE + per-head L2 norm (+attn_scale*log2e on Q) ----------------
__global__ __launch_bounds__(256) void rope_norm(const u16* __restrict__ qkv, const float* __restrict__ fc,
                                                 const float* __restrict__ scale_p,
                                                 u16* __restrict__ Qo, u16* __restrict__ Ko) {
  int gid = blockIdx.x;
  int bs = gid >> 2;
  int s = bs & (S_ - 1);
  int b = bs >> 11;
  int w = threadIdx.x >> 6, l = threadIdx.x & 63;
  int h = (gid & 3)*4 + w;
  float2 cs = ((const float2*)fc)[(size_t)s*64 + l];
  float scale = scale_p[0] * 1.4426950408889634f;  // fold log2(e) for exp2 softmax
  const u16* base = qkv + (size_t)bs * D3_;
  size_t obase = ((size_t)(b*H_ + h) * S_ + s) * HD_ + 2*l;
  {
    const u16* p = base + h*HD_ + 2*l;
    float x0 = bf2f(p[0]), x1 = bf2f(p[1]);
    float r0 = x0*cs.x - x1*cs.y;
    float r1 = x1*cs.x + x0*cs.y;
    float t = r0*r0 + r1*r1;
#pragma unroll
    for (int mk = 1; mk < 64; mk <<= 1) t += __shfl_xor(t, mk, 64);
    float inv = scale / (sqrtf(t) + 1e-6f);
    u16x2 o; o[0] = f2bf(r0*inv); o[1] = f2bf(r1*inv);
    *(u16x2*)(Qo + obase) = o;
  }
  {
    const u16* p = base + D_ + h*HD_ + 2*l;
    float x0 = bf2f(p[0]), x1 = bf2f(p[1]);
    float r0 = x0*cs.x - x1*cs.y;
    float r1 = x1*cs.x + x0*cs.y;
    float t = r0*r0 + r1*r1;
#pragma unroll
    for (int mk = 1; mk < 64; mk <<= 1) t += __shfl_xor(t, mk, 64);
    float inv = 1.0f / (sqrtf(t) + 1e-6f);
    u16x2 o; o[0] = f2bf(r0*inv); o[1] = f2bf(r1*inv);
    *(u16x2*)(Ko + obase) = o;
  }
}

// ---------------- V transpose: qkv v-slice [B,S,H,HD] -> Vt [B*H, HD, S] ----------------
__global__ __launch_bounds__(256) void v_trans(const u16* __restrict__ qkv, u16* __restrict__ Vt) {
  __shared__ u16 vt[64][136];
  int blk = blockIdx.x;
  int bh = blk >> 5, st = blk & 31;
  int b = bh >> 4, h = bh & 15;
  int s0 = st * 64;
  int tid = threadIdx.x;
#pragma unroll
  for (int i = 0; i < 4; ++i) {
    int idx = tid + i*256;
    int row = idx >> 4, ch = idx & 15;
    u16x8 v = *(const u16x8*)(qkv + (size_t)(b*S_ + s0 + row) * D3_ + 2*D_ + h*HD_ + ch*8);
    *(u16x8*)(&vt[row][ch*8]) = v;
  }
  __syncthreads();
#pragma unroll
  for (int p = 0; p < 2; ++p) {
    int d = p*64 + (tid >> 2);
    int q = (tid & 3) * 16;
    u16x8 t0, t1;
#pragma unroll
    for (int i = 0; i < 8; ++i) t0[i] = vt[q + i][d];
#pragma unroll
    for (int i = 0; i < 8; ++i) t1[i] = vt[q + 8 + i][d];
    u16* dst = Vt + ((size_t)bh * HD_ + d) * S_ + s0 + q;
    *(u16x8*)dst = t0;
    *(u16x8*)(dst + 8) = t1;
  }
}

// ---------------- causal flash attention (swapped QK^T, lane-local softmax, defer-max) ----------------
__global__ __launch_bounds__(512) void flash_attn(const u16* __restrict__ Qh, const u16* __restrict__ Kh,
                                                  const u16* __restrict__ Vt, u16* __restrict__ AO) {
  __shared__ __align__(16) u16 lK[2][64*128];   // 32 KB
  __shared__ __align__(16) u16 lV[128*64];      // 16 KB
  __shared__ __align__(16) u16 lP[8][16*72];    // 18 KB
  const int i0 = (int)blockIdx.x;               // 0..511
  const int k5 = i0 & 255;
  const int bh = k5 >> 3;
  const int jj = k5 & 7;
  const int qt = (i0 < 256) ? (15 - jj) : jj;   // heavy half first
  const int tid = threadIdx.x, w = tid >> 6, l = tid & 63;
  const int lr = l & 15, lg = l >> 4;
  const int b = bh >> 4, h = bh & 15;

  bf16x8 qf[4];
  {
    const u16* qp = Qh + ((size_t)bh * S_ + qt*128 + w*16 + lr) * HD_ + lg*8;
#pragma unroll
    for (int ks = 0; ks < 4; ++ks) qf[ks] = *(const bf16x8*)(qp + ks*32);
  }
  float m0 = -__builtin_inff(), ls0 = 0.f;      // running max/sum for q = w*16 + lr
  f32x4 oacc[8] = {};

  int krow[2], kcol[2], vrow[2], vcol[2], dstb[2];
#pragma unroll
  for (int p = 0; p < 2; ++p) {
    int off = p*8192 + tid*16;
    krow[p] = off >> 8; kcol[p] = (off & 255) ^ ((krow[p] & 7) << 4);
    vrow[p] = off >> 7; vcol[p] = (off & 127) ^ ((vrow[p] & 7) << 4);
    dstb[p] = p*8192 + w*1024;
  }
  const char* Kb = (const char*)(Kh + (size_t)bh * S_ * HD_);
  const char* Vb = (const char*)(Vt + (size_t)bh * HD_ * S_);

#define STAGE_K(nb, kt_) do {                                                       \
    _Pragma("unroll")                                                               \
    for (int p_ = 0; p_ < 2; ++p_)                                                  \
      gload_lds16(Kb + (size_t)((kt_)*64 + krow[p_])*256 + kcol[p_],                \
                  (char*)lK[nb] + dstb[p_]);                                        \
  } while (0)
#define STAGE_V(kt_) do {                                                           \
    _Pragma("unroll")                                                               \
    for (int p_ = 0; p_ < 2; ++p_)                                                  \
      gload_lds16(Vb + (size_t)vrow[p_]*(S_*2) + (kt_)*128 + vcol[p_],              \
                  (char*)lV + dstb[p_]);                                            \
  } while (0)

  const int nt = 2*qt + 2;
  STAGE_K(0, 0);
  STAGE_V(0);
  int cur = 0;
  for (int kt = 0; kt < nt; ++kt) {
    asm volatile("s_waitcnt vmcnt(2)" ::: "memory");
    __builtin_amdgcn_s_barrier();
    asm volatile("" ::: "memory");
    const char* lKb = (const char*)lK[cur];

    // swapped QK^T: sc[f][j] = S[k = kt*64 + f*16 + lg*4 + j][q = qt*128 + w*16 + lr]
    f32x4 sc[4] = {};
    __builtin_amdgcn_s_setprio(1);
#pragma unroll
    for (int ks = 0; ks < 4; ++ks) {
#pragma unroll
      for (int f = 0; f < 4; ++f) {
        int row = f*16 + lr;
        bf16x8 kf = *(const bf16x8*)(lKb + row*256 + ((ks*64 + lg*16) ^ ((row & 7) << 4)));
        sc[f] = __builtin_amdgcn_mfma_f32_16x16x32_bf16(kf, qf[ks], sc[f], 0, 0, 0);
      }
    }
    __builtin_amdgcn_s_setprio(0);
    if (kt < nt-1) STAGE_K(cur ^ 1, kt + 1);   // prefetch next K under softmax

    if (kt >= nt-2) {  // diagonal tiles: mask k > q
#pragma unroll
      for (int f = 0; f < 4; ++f)
#pragma unroll
        for (int j = 0; j < 4; ++j)
          if (kt*64 + f*16 + lg*4 + j > qt*128 + w*16 + lr) sc[f][j] = -__builtin_inff();
    }
    // lane-local online softmax with defer-max
    float pmax = sc[0][0];
#pragma unroll
    for (int f = 0; f < 4; ++f)
#pragma unroll
      for (int j = 0; j < 4; ++j) pmax = fmaxf(pmax, sc[f][j]);
    pmax = fmaxf(pmax, __shfl_xor(pmax, 16, 64));
    pmax = fmaxf(pmax, __shfl_xor(pmax, 32, 64));
    const int norescale = __all(pmax - m0 <= 8.0f);
    float mn;
    float resc = 0.f;
    if (norescale) {
      mn = m0;                       // keep old max; P bounded by 2^8
    } else {
      mn = fmaxf(m0, pmax);
      resc = exp2f(m0 - mn);
      m0 = mn;
    }
    float rsum = 0.f;
#pragma unroll
    for (int f = 0; f < 4; ++f)
#pragma unroll
      for (int j = 0; j < 4; ++j) {
        float p = exp2f(sc[f][j] - mn);
        sc[f][j] = p;
        rsum += p;
      }
    rsum += __shfl_xor(rsum, 16, 64);
    rsum += __shfl_xor(rsum, 32, 64);
    if (norescale) {
      ls0 = ls0 + rsum;
    } else {
      ls0 = ls0 * resc + rsum;
      float rescj[4];
#pragma unroll
      for (int j = 0; j < 4; ++j) rescj[j] = __shfl(resc, lg*4 + j, 64);
#pragma unroll
      for (int fd = 0; fd < 8; ++fd)
#pragma unroll
        for (int j = 0; j < 4; ++j) oacc[fd][j] *= rescj[j];
    }
    // P[q=lr][k] packed write: one b64 per f
#pragma unroll
    for (int f = 0; f < 4; ++f) {
      u16x4 pk;
#pragma unroll
      for (int j = 0; j < 4; ++j) pk[j] = f2bf(sc[f][j]);
      *(u16x4*)((char*)lP[w] + lr*144 + f*32 + lg*8) = pk;
    }

    if (kt < nt-1) { asm volatile("s_waitcnt vmcnt(2)" ::: "memory"); }
    else           { asm volatile("s_waitcnt vmcnt(0)" ::: "memory"); }
    __builtin_amdgcn_s_barrier();
    asm volatile("" ::: "memory");
    // PV
    __builtin_amdgcn_s_setprio(1);
#pragma unroll
    for (int ks = 0; ks < 2; ++ks) {
      bf16x8 pf = *(const bf16x8*)((const char*)lP[w] + lr*144 + ks*64 + lg*16);
#pragma unroll
      for (int fd = 0; fd < 8; ++fd) {
        int row = fd*16 + lr;
        bf16x8 vf = *(const bf16x8*)((const char*)lV + row*128 + ((ks*64 + lg*16) ^ ((row & 7) << 4)));
        oacc[fd] = __builtin_amdgcn_mfma_f32_16x16x32_bf16(pf, vf, oacc[fd], 0, 0, 0);
      }
    }
    __builtin_amdgcn_s_setprio(0);
    asm volatile("" ::: "memory");
    __builtin_amdgcn_s_barrier();
    asm volatile("" ::: "memory");
    if (kt < nt-1) STAGE_V(kt + 1);
    cur ^= 1;
  }
#undef STAGE_K
#undef STAGE_V
  // epilogue: 1/ls redistributed to j-space
  float invl[4];
#pragma unroll
  for (int j = 0; j < 4; ++j) {
    float lsj = __shfl(ls0, lg*4 + j, 64);
    invl[j] = 1.0f / lsj;
  }
#pragma unroll
  for (int fd = 0; fd < 8; ++fd)
#pragma unroll
    for (int j = 0; j < 4; ++j) {
      int qq = qt*128 + w*16 + lg*4 + j;
      int dd = fd*16 + lr;
      float v = oacc[fd][j] * invl[j];
      AO[((size_t)b*S_ + qq)*D_ + h*HD_ + dd] = f2bf(v);
    }
}

// ---------------- launch ----------------
extern "C" void kernel_launch(void* const* d_in, const int* in_sizes, int n_in,
                              void* d_out, int out_size, void* d_ws, size_t ws_size,
                              hipStream_t stream) {
  const float* x        = (const float*)d_in[0];
  const float* w_qkv    = (const float*)d_in[1];
  const float* w_out    = (const float*)d_in[2];
  const float* attn_sc  = (const float*)d_in[3];
  const float* freqs    = (const float*)d_in[4];

  if (ws_size < 167772160u) return;  // need 160 MB scratch

  char* ws = (char*)d_ws;
  u16* xbf  = (u16*)(ws);                 //  16 MB  [4096][2048]
  u16* wqbf = (u16*)(ws + 16777216);      //  24 MB  [6144][2048]
  u16* wobf = (u16*)(ws + 41943040);      //   8 MB  [2048][2048]
  u16* qkv  = (u16*)(ws + 50331648);      //  48 MB  [4096][6144]
  u16* Qh   = (u16*)(ws + 100663296);     //  16 MB  [B*H][S][HD]
  u16* Kh   = (u16*)(ws + 117440512);     //  16 MB  [B*H][S][HD]
  u16* Vt   = (u16*)(ws + 134217728);     //  16 MB  [B*H][HD][S]
  u16* AO   = (u16*)(ws + 150994944);     //  16 MB  [4096][2048]

  castk3<<<12288, 256, 0, stream>>>(x, w_qkv, w_out, xbf, wqbf, wobf);

  // QKV: 256x384 tiles -> (16, 16) = 256 blocks = exact 1 round
  gemm384<1><<<dim3(16, 16), 512, 0, stream>>>(xbf, wqbf, qkv, 4096, 6144, 2048);

  rope_norm<<<16384, 256, 0, stream>>>(qkv, freqs, attn_sc, Qh, Kh);
  v_trans<<<1024, 256, 0, stream>>>(qkv, Vt);

  flash_attn<<<512, 512, 0, stream>>>(Qh, Kh, Vt, AO);

  // out-projection: 128x128 tiles, (16, 32) = 512 blocks, 2 blocks/CU
  gemm_bt<0><<<dim3(16, 32), 256, 0, stream>>>(AO, wobf, (float*)d_out, 4096, 2048, 2048);
}